// Round 11
// baseline (262.194 us; speedup 1.0000x reference)
//
#include <hip/hip_runtime.h>

#define N_USERS 400000
#define N_ITEMS 200000
#define NNODES  600000   // N_USERS + N_ITEMS
#define D 64
#define B 8192
#define NBKT 8

// ---------------------------------------------------------------------------
// bf16 helpers
// ---------------------------------------------------------------------------
__device__ __forceinline__ float bflo(unsigned u) { return __uint_as_float(u << 16); }
__device__ __forceinline__ float bfhi(unsigned u) { return __uint_as_float(u & 0xffff0000u); }
__device__ __forceinline__ unsigned f2bf(float f) {   // round-to-nearest-even
    unsigned u = __float_as_uint(f);
    unsigned r = u + 0x7fffu + ((u >> 16) & 1u);
    return r >> 16;
}

// acc[0..7] += v * bf16x8(word4)
__device__ __forceinline__ void unpack_fma(float* acc, uint4 wv, float v) {
    acc[0] += v * bflo(wv.x); acc[1] += v * bfhi(wv.x);
    acc[2] += v * bflo(wv.y); acc[3] += v * bfhi(wv.y);
    acc[4] += v * bflo(wv.z); acc[5] += v * bfhi(wv.z);
    acc[6] += v * bflo(wv.w); acc[7] += v * bfhi(wv.w);
}

// Bucket map balanced by expected edge count.
__device__ __forceinline__ int bucket_of(int r) {
    return (r < N_USERS) ? (r / 100000) : (4 + (r - N_USERS) / 50000);
}

// ---------------------------------------------------------------------------
// scans
// ---------------------------------------------------------------------------
__global__ void k_scan1(int* __restrict__ deg, int* __restrict__ sums,
                        float* __restrict__ dinv, int n) {
    __shared__ int lds[256];
    int i = blockIdx.x * 256 + threadIdx.x;
    int v = (i < n) ? deg[i] : 0;
    if (i < n) dinv[i] = (v > 0) ? (float)(1.0 / sqrt((double)v)) : 0.0f;
    lds[threadIdx.x] = v;
    __syncthreads();
    for (int off = 1; off < 256; off <<= 1) {
        int t = (threadIdx.x >= off) ? lds[threadIdx.x - off] : 0;
        __syncthreads();
        lds[threadIdx.x] += t;
        __syncthreads();
    }
    int inc = lds[threadIdx.x];
    if (i < n) deg[i] = inc - v;
    if (threadIdx.x == 255) sums[blockIdx.x] = inc;
}

__global__ void k_scan2(int* __restrict__ sums, int n) {
    __shared__ int lds[1024];
    __shared__ int carry;
    if (threadIdx.x == 0) carry = 0;
    __syncthreads();
    for (int base = 0; base < n; base += 1024) {
        int i = base + threadIdx.x;
        int v = (i < n) ? sums[i] : 0;
        lds[threadIdx.x] = v;
        __syncthreads();
        for (int off = 1; off < 1024; off <<= 1) {
            int t = (threadIdx.x >= off) ? lds[threadIdx.x - off] : 0;
            __syncthreads();
            lds[threadIdx.x] += t;
            __syncthreads();
        }
        int inc = lds[threadIdx.x];
        if (i < n) sums[i] = (inc - v) + carry;
        __syncthreads();
        if (threadIdx.x == 1023) carry += lds[1023];
        __syncthreads();
    }
}

__global__ void k_scan3(const int* __restrict__ deg, const int* __restrict__ sums,
                        int* __restrict__ row_ptr, int* __restrict__ nextp, int nnz) {
    int i = blockIdx.x * blockDim.x + threadIdx.x;
    if (i >= NNODES) return;
    int rp = deg[i] + sums[i >> 8];
    row_ptr[i] = rp;
    nextp[i] = rp;
    if (i == 0) row_ptr[NNODES] = nnz;
}

// ---------------------------------------------------------------------------
// FAT-A: XCD-filtered deg histogram (ILP-8) + sample seed. NO mask stream:
// R7/R9 accounting showed the fused stream+hist kernel (65-73us, WRITE 42MB)
// is slower than serial standalone parts (~27+~18) -- the 153MB stream evicts
// the deg atomic lines from L2. The stream pairs badly with ANY kernel that
// needs L2 residency; it runs alone (k_sizes below).
// bid < nhist: hist supertile bid>>3, bucket filter x=bid&7 (XCD-local).
// else: seed tail blocks.
// ---------------------------------------------------------------------------
__global__ void k_fatA(const int* __restrict__ rows, int* __restrict__ deg,
                       const int* __restrict__ users, const int* __restrict__ pos,
                       const int* __restrict__ neg,
                       char* __restrict__ flag1, char* __restrict__ flag2,
                       int nnz, int nhist) {
    int bid = blockIdx.x;
    int t = threadIdx.x;
    if (bid < nhist) {
        int x = bid & 7;
        int st = bid >> 3;
        int ebase = st * 2048 + t;
        int rr[8];
        #pragma unroll
        for (int k = 0; k < 8; ++k) {
            int e = ebase + k * 256;
            rr[k] = (e < nnz) ? rows[e] : -1;
        }
        #pragma unroll
        for (int k = 0; k < 8; ++k) {
            if (rr[k] >= 0 && bucket_of(rr[k]) == x) atomicAdd(&deg[rr[k]], 1);
        }
    } else {
        int slot2 = (bid - nhist) * 256 + t;
        if (slot2 >= 3 * B) return;
        int set = slot2 / B;
        int b = slot2 - set * B;
        int r;
        if (set == 0)      r = users[b];
        else if (set == 1) r = N_USERS + pos[b];
        else               r = N_USERS + neg[b];
        flag2[r] = 1;
        flag1[r] = 1;
    }
}

// ---------------------------------------------------------------------------
// sizes[r] = popcount of prefix-mask row. STANDALONE streaming pass (the only
// reader of the 153.6MB masks). 16 threads/row, int4 loads, shfl reduce.
// ---------------------------------------------------------------------------
__global__ void k_sizes(const int* __restrict__ um, const int* __restrict__ im,
                        int* __restrict__ sizes) {
    int gtid = blockIdx.x * blockDim.x + threadIdx.x;
    int r = gtid >> 4;
    int q = gtid & 15;
    if (r >= NNODES) return;
    const int4* p = (const int4*)((r < N_USERS) ? um + (size_t)r * D
                                                : im + (size_t)(r - N_USERS) * D);
    int4 v = p[q];
    int s = v.x + v.y + v.z + v.w;
    s += __shfl_xor(s, 1);
    s += __shfl_xor(s, 2);
    s += __shfl_xor(s, 4);
    s += __shfl_xor(s, 8);
    if (q == 0) sizes[r] = s;
}

// ---------------------------------------------------------------------------
// FAT2: XCD-filtered scatter (ILP-8) || COO mark-pass1. (R9 - validated:
// fat2 left the top-5 after ILP-8; 8 independent atomic chains per lane.)
// pass1 race: monotone 0->1, benign superset.
// ---------------------------------------------------------------------------
__global__ void k_fat2(const int* __restrict__ rows, const int* __restrict__ cols,
                       int* __restrict__ nextp, int* __restrict__ pcol,
                       char* __restrict__ flag2, int nnz) {
    int bid = blockIdx.x;
    int x = bid & 7;
    int g = bid >> 3;
    int st = g >> 1;
    int slot = g & 1;
    int t = threadIdx.x;
    if (slot == 0) {
        int ebase = st * 2048 + t;
        int rr[8];
        #pragma unroll
        for (int k = 0; k < 8; ++k) {
            int e = ebase + k * 256;
            rr[k] = (e < nnz) ? rows[e] : -1;
        }
        #pragma unroll
        for (int k = 0; k < 8; ++k) {
            if (rr[k] >= 0 && bucket_of(rr[k]) == x) {
                int c = cols[ebase + k * 256];
                int p = atomicAdd(&nextp[rr[k]], 1);
                pcol[p] = c;
            }
        }
    } else {
        int e = (st * 8 + x) * 256 + t;
        if (e >= nnz) return;
        if (flag2[rows[e]]) flag2[cols[e]] = 1;
    }
}

// ---------------------------------------------------------------------------
// COO mark pass2 + per-block flag2 counts. Standalone (no stream sharing).
// ---------------------------------------------------------------------------
__global__ void k_pass2(const int* __restrict__ rows, const int* __restrict__ cols,
                        const char* __restrict__ flag2, char* __restrict__ flag1,
                        int* __restrict__ cnt2, int nnz, int eb) {
    int bid = blockIdx.x;
    int t = threadIdx.x;
    if (bid < eb) {
        int e = bid * 256 + t;
        if (e < nnz && flag2[rows[e]]) flag1[cols[e]] = 1;
        return;
    }
    int tb = bid - eb;
    int r = tb * 256 + t;
    char f = (r < NNODES) ? flag2[r] : 0;
    if (f) flag1[r] = 1;
    unsigned long long bal = __ballot(f != 0);
    __shared__ int ws[4];
    int lane = t & 63, wv = t >> 6;
    if (lane == 0) ws[wv] = (int)__popcll(bal);
    __syncthreads();
    if (t == 0) cnt2[tb] = ws[0] + ws[1] + ws[2] + ws[3];
}

// per-block flag1 counts (flag1 stable after pass2)
__global__ void k_cnt1(const char* __restrict__ flag1, int* __restrict__ cnt1) {
    int tb = blockIdx.x;
    int t = threadIdx.x;
    int r = tb * 256 + t;
    char f = (r < NNODES) ? flag1[r] : 0;
    unsigned long long bal = __ballot(f != 0);
    __shared__ int ws[4];
    int lane = t & 63, wv = t >> 6;
    if (lane == 0) ws[wv] = (int)__popcll(bal);
    __syncthreads();
    if (t == 0) cnt1[tb] = ws[0] + ws[1] + ws[2] + ws[3];
}

// single-block exclusive scan of TWO count arrays (in place) + totals
__global__ void k_scan_dual(int* __restrict__ a, int* __restrict__ b, int n,
                            int* __restrict__ totA, int* __restrict__ totB) {
    __shared__ int lds[1024];
    __shared__ int carry;
    for (int pass = 0; pass < 2; ++pass) {
        int* arr = pass ? b : a;
        if (threadIdx.x == 0) carry = 0;
        __syncthreads();
        for (int base = 0; base < n; base += 1024) {
            int i = base + threadIdx.x;
            int v = (i < n) ? arr[i] : 0;
            lds[threadIdx.x] = v;
            __syncthreads();
            for (int off = 1; off < 1024; off <<= 1) {
                int t = (threadIdx.x >= off) ? lds[threadIdx.x - off] : 0;
                __syncthreads();
                lds[threadIdx.x] += t;
                __syncthreads();
            }
            int inc = lds[threadIdx.x];
            if (i < n) arr[i] = (inc - v) + carry;
            __syncthreads();
            if (threadIdx.x == 1023) carry += lds[1023];
            __syncthreads();
        }
        if (threadIdx.x == 0) { if (pass) *totB = carry; else *totA = carry; }
        __syncthreads();
    }
}

// ballot-rank fill of both worklists (sorted order -> pcol/y1 locality)
__global__ void k_fill(const char* __restrict__ flag1, const char* __restrict__ flag2,
                       const int* __restrict__ cnt1, const int* __restrict__ cnt2,
                       int* __restrict__ wl1, int* __restrict__ wl2) {
    int tb = blockIdx.x;
    int t = threadIdx.x;
    int r = tb * 256 + t;
    bool a = (r < NNODES) && flag1[r];
    bool b = (r < NNODES) && flag2[r];
    int lane = t & 63, wv = t >> 6;
    unsigned long long lt = (1ull << lane) - 1ull;
    unsigned long long ba = __ballot(a);
    unsigned long long bb = __ballot(b);
    __shared__ int wa[4], wb[4];
    if (lane == 0) { wa[wv] = (int)__popcll(ba); wb[wv] = (int)__popcll(bb); }
    __syncthreads();
    int offA = 0, offB = 0;
    for (int i = 0; i < wv; ++i) { offA += wa[i]; offB += wb[i]; }
    if (a) wl1[cnt1[tb] + offA + (int)__popcll(ba & lt)] = r;
    if (b) wl2[cnt2[tb] + offB + (int)__popcll(bb & lt)] = r;
}

// ---------------------------------------------------------------------------
// Layer-1 SPMM over the wl1 worklist (dense waves). 8 threads/row, unroll x2.
// ---------------------------------------------------------------------------
__global__ void k_spmm1(const int* __restrict__ row_ptr, const int* __restrict__ pcol,
                        const float* __restrict__ dinv, const int* __restrict__ sizes,
                        const int* __restrict__ wl1, const int* __restrict__ wl1_cnt,
                        const float* __restrict__ ue, const float* __restrict__ ie,
                        unsigned* __restrict__ y1) {
    int tid = blockIdx.x * blockDim.x + threadIdx.x;
    int w = tid >> 3;
    if (w >= *wl1_cnt) return;
    int r = wl1[w];
    int c8 = (tid & 7) << 3;          // f32 col base
    int s = row_ptr[r];
    int e = row_ptr[r + 1];
    float dr = dinv[r];
    float acc[8] = {0.f, 0.f, 0.f, 0.f, 0.f, 0.f, 0.f, 0.f};
    int i = s;
    for (; i + 1 < e; i += 2) {
        int c0 = pcol[i], c1 = pcol[i + 1];
        float v0 = dr * dinv[c0], v1 = dr * dinv[c1];
        int sz0 = sizes[c0], sz1 = sizes[c1];
        const float* p0 = ((c0 < N_USERS) ? ue + (size_t)c0 * D
                                          : ie + (size_t)(c0 - N_USERS) * D) + c8;
        const float* p1 = ((c1 < N_USERS) ? ue + (size_t)c1 * D
                                          : ie + (size_t)(c1 - N_USERS) * D) + c8;
        float4 a0 = *(const float4*)p0;
        float4 a1 = *(const float4*)(p0 + 4);
        float4 b0 = *(const float4*)p1;
        float4 b1 = *(const float4*)(p1 + 4);
        acc[0] += v0 * ((c8 + 0 < sz0) ? a0.x : 0.f) + v1 * ((c8 + 0 < sz1) ? b0.x : 0.f);
        acc[1] += v0 * ((c8 + 1 < sz0) ? a0.y : 0.f) + v1 * ((c8 + 1 < sz1) ? b0.y : 0.f);
        acc[2] += v0 * ((c8 + 2 < sz0) ? a0.z : 0.f) + v1 * ((c8 + 2 < sz1) ? b0.z : 0.f);
        acc[3] += v0 * ((c8 + 3 < sz0) ? a0.w : 0.f) + v1 * ((c8 + 3 < sz1) ? b0.w : 0.f);
        acc[4] += v0 * ((c8 + 4 < sz0) ? a1.x : 0.f) + v1 * ((c8 + 4 < sz1) ? b1.x : 0.f);
        acc[5] += v0 * ((c8 + 5 < sz0) ? a1.y : 0.f) + v1 * ((c8 + 5 < sz1) ? b1.y : 0.f);
        acc[6] += v0 * ((c8 + 6 < sz0) ? a1.z : 0.f) + v1 * ((c8 + 6 < sz1) ? b1.z : 0.f);
        acc[7] += v0 * ((c8 + 7 < sz0) ? a1.w : 0.f) + v1 * ((c8 + 7 < sz1) ? b1.w : 0.f);
    }
    if (i < e) {
        int c = pcol[i];
        float v = dr * dinv[c];
        int sz = sizes[c];
        const float* p = ((c < N_USERS) ? ue + (size_t)c * D
                                        : ie + (size_t)(c - N_USERS) * D) + c8;
        float4 e0 = *(const float4*)p;
        float4 e1 = *(const float4*)(p + 4);
        acc[0] += v * ((c8 + 0 < sz) ? e0.x : 0.f);
        acc[1] += v * ((c8 + 1 < sz) ? e0.y : 0.f);
        acc[2] += v * ((c8 + 2 < sz) ? e0.z : 0.f);
        acc[3] += v * ((c8 + 3 < sz) ? e0.w : 0.f);
        acc[4] += v * ((c8 + 4 < sz) ? e1.x : 0.f);
        acc[5] += v * ((c8 + 5 < sz) ? e1.y : 0.f);
        acc[6] += v * ((c8 + 6 < sz) ? e1.z : 0.f);
        acc[7] += v * ((c8 + 7 < sz) ? e1.w : 0.f);
    }
    uint4 o;
    o.x = f2bf(acc[0]) | (f2bf(acc[1]) << 16);
    o.y = f2bf(acc[2]) | (f2bf(acc[3]) << 16);
    o.z = f2bf(acc[4]) | (f2bf(acc[5]) << 16);
    o.w = f2bf(acc[6]) | (f2bf(acc[7]) << 16);
    *(uint4*)(y1 + (size_t)r * 32 + (tid & 7) * 4) = o;
}

// ---------------------------------------------------------------------------
// Layer-2 bf16 SPMM over the wl2 worklist: x2[r] = sum val * y1[col].
// ---------------------------------------------------------------------------
__global__ void k_spmm2(const int* __restrict__ row_ptr, const int* __restrict__ pcol,
                        const float* __restrict__ dinv,
                        const int* __restrict__ wl2, const int* __restrict__ wl2_cnt,
                        const unsigned* __restrict__ y1, unsigned* __restrict__ x2) {
    int tid = blockIdx.x * blockDim.x + threadIdx.x;
    int w = tid >> 3;
    if (w >= *wl2_cnt) return;
    int r = wl2[w];
    int cp = (tid & 7) << 2;
    int s = row_ptr[r];
    int e = row_ptr[r + 1];
    float dr = dinv[r];
    float acc[8] = {0.f, 0.f, 0.f, 0.f, 0.f, 0.f, 0.f, 0.f};
    int i = s;
    for (; i + 1 < e; i += 2) {
        int c0 = pcol[i], c1 = pcol[i + 1];
        float v0 = dr * dinv[c0], v1 = dr * dinv[c1];
        uint4 w0 = *(const uint4*)(y1 + (size_t)c0 * 32 + cp);
        uint4 w1 = *(const uint4*)(y1 + (size_t)c1 * 32 + cp);
        unpack_fma(acc, w0, v0);
        unpack_fma(acc, w1, v1);
    }
    if (i < e) {
        int c0 = pcol[i];
        float v0 = dr * dinv[c0];
        uint4 w0 = *(const uint4*)(y1 + (size_t)c0 * 32 + cp);
        unpack_fma(acc, w0, v0);
    }
    uint4 o;
    o.x = f2bf(acc[0]) | (f2bf(acc[1]) << 16);
    o.y = f2bf(acc[2]) | (f2bf(acc[3]) << 16);
    o.z = f2bf(acc[4]) | (f2bf(acc[5]) << 16);
    o.w = f2bf(acc[6]) | (f2bf(acc[7]) << 16);
    *(uint4*)(x2 + (size_t)r * 32 + cp) = o;
}

// ---------------------------------------------------------------------------
// Final sampled layer, fused epilogue + ego.
// ---------------------------------------------------------------------------
__global__ void k_spmm3(const int* __restrict__ row_ptr, const int* __restrict__ pcol,
                        const float* __restrict__ dinv, const int* __restrict__ sizes,
                        const float* __restrict__ ue, const float* __restrict__ ie,
                        const unsigned* __restrict__ y1, const unsigned* __restrict__ x2,
                        const int* __restrict__ users, const int* __restrict__ pos,
                        const int* __restrict__ neg, float* __restrict__ out) {
    int tid = blockIdx.x * blockDim.x + threadIdx.x;
    int slot = tid >> 3;
    if (slot >= 3 * B) return;
    int cp = (tid & 7) << 2;          // uint base
    int c8 = (tid & 7) << 3;          // f32 col base
    int set = slot / B;
    int b = slot - set * B;
    int r;
    if (set == 0)      r = users[b];
    else if (set == 1) r = N_USERS + pos[b];
    else               r = N_USERS + neg[b];
    int s = row_ptr[r];
    int e = row_ptr[r + 1];
    float dr = dinv[r];
    float acc[8] = {0.f, 0.f, 0.f, 0.f, 0.f, 0.f, 0.f, 0.f};
    uint4 g1 = *(const uint4*)(y1 + (size_t)r * 32 + cp);
    uint4 g2 = *(const uint4*)(x2 + (size_t)r * 32 + cp);
    unpack_fma(acc, g1, 1.0f);
    unpack_fma(acc, g2, 1.0f);
    int i = s;
    for (; i + 1 < e; i += 2) {
        int c0 = pcol[i], c1 = pcol[i + 1];
        float v0 = dr * dinv[c0], v1 = dr * dinv[c1];
        uint4 w0 = *(const uint4*)(x2 + (size_t)c0 * 32 + cp);
        uint4 w1 = *(const uint4*)(x2 + (size_t)c1 * 32 + cp);
        unpack_fma(acc, w0, v0);
        unpack_fma(acc, w1, v1);
    }
    if (i < e) {
        int c0 = pcol[i];
        float v0 = dr * dinv[c0];
        uint4 w0 = *(const uint4*)(x2 + (size_t)c0 * 32 + cp);
        unpack_fma(acc, w0, v0);
    }
    const float* p = ((r < N_USERS) ? ue + (size_t)r * D
                                    : ie + (size_t)(r - N_USERS) * D) + c8;
    float4 e0 = *(const float4*)p;
    float4 e1 = *(const float4*)(p + 4);
    int sz = sizes[r];
    e0.x = (c8 + 0 < sz) ? e0.x : 0.f; e0.y = (c8 + 1 < sz) ? e0.y : 0.f;
    e0.z = (c8 + 2 < sz) ? e0.z : 0.f; e0.w = (c8 + 3 < sz) ? e0.w : 0.f;
    e1.x = (c8 + 4 < sz) ? e1.x : 0.f; e1.y = (c8 + 5 < sz) ? e1.y : 0.f;
    e1.z = (c8 + 6 < sz) ? e1.z : 0.f; e1.w = (c8 + 7 < sz) ? e1.w : 0.f;
    float4 oa, ob;
    oa.x = (e0.x + acc[0]) * 0.25f; oa.y = (e0.y + acc[1]) * 0.25f;
    oa.z = (e0.z + acc[2]) * 0.25f; oa.w = (e0.w + acc[3]) * 0.25f;
    ob.x = (e1.x + acc[4]) * 0.25f; ob.y = (e1.y + acc[5]) * 0.25f;
    ob.z = (e1.z + acc[6]) * 0.25f; ob.w = (e1.w + acc[7]) * 0.25f;
    float* o0 = out + (size_t)slot * D + c8;
    float* o1 = out + (size_t)(3 * B + slot) * D + c8;
    *(float4*)o0 = oa; *(float4*)(o0 + 4) = ob;
    *(float4*)o1 = e0; *(float4*)(o1 + 4) = e1;
}

extern "C" void kernel_launch(void* const* d_in, const int* in_sizes, int n_in,
                              void* d_out, int out_size, void* d_ws, size_t ws_size,
                              hipStream_t stream) {
    const float* ue   = (const float*)d_in[0];
    const float* ie   = (const float*)d_in[1];
    const int*   um   = (const int*)d_in[2];
    const int*   im   = (const int*)d_in[3];
    const int*   rows = (const int*)d_in[4];
    const int*   cols = (const int*)d_in[5];
    const int*   users = (const int*)d_in[7];
    const int*   pos   = (const int*)d_in[8];
    const int*   neg   = (const int*)d_in[9];
    int nnz = in_sizes[4];

    float* out = (float*)d_out;

    // workspace layout (16B-aligned bf16 node buffers first)
    unsigned short* Y1 = (unsigned short*)d_ws;         // NNODES*D bf16
    unsigned short* X2 = Y1 + (size_t)NNODES * D;       // NNODES*D bf16
    int*   deg     = (int*)(X2 + (size_t)NNODES * D);   // NNODES
    int*   row_ptr = deg + NNODES;                      // NNODES+1
    int*   nextp   = row_ptr + NNODES + 1;              // NNODES
    int*   sizes   = nextp + NNODES;                    // NNODES
    int*   sums    = sizes + NNODES;                    // up to 4096
    int*   wcnt    = sums + 4096;                       // [0]=wl1_cnt [1]=wl2_cnt
    int*   cnt1    = wcnt + 16;                         // 2344 (+pad)
    int*   cnt2    = cnt1 + 2360;                       // 2344 (+pad)
    float* dinv    = (float*)(cnt2 + 2360);             // NNODES
    int*   pcol    = (int*)(dinv + NNODES);             // nnz
    char*  flag1   = (char*)(pcol + nnz);               // NNODES
    char*  flag2   = flag1 + NNODES;                    // NNODES
    int*   wl1     = (int*)(((uintptr_t)(flag2 + NNODES) + 15) & ~(uintptr_t)15);
    int*   wl2     = wl1 + NNODES;

    const int blk = 256;
    const int scan_blocks = (NNODES + 255) / 256;       // 2344
    int chunks = (nnz + 255) / 256;                     // 4688
    int nst = (chunks + 7) / 8;                         // 586 supertiles
    int nhist = nst * 8;                                // hist blocks (XCD x supertile)
    int seed_blocks = (3 * B + blk - 1) / blk;          // 96

    hipMemsetAsync(deg, 0, (size_t)NNODES * sizeof(int), stream);
    hipMemsetAsync(flag1, 0, (size_t)2 * NNODES, stream);

    // --- FAT-A: histX(ILP-8) + seed (quiet L2 for deg atomics) ---
    k_fatA<<<nhist + seed_blocks, blk, 0, stream>>>(rows, deg, users, pos, neg,
                                                    flag1, flag2, nnz, nhist);

    // --- sizes: standalone mask stream (pairs badly with everything) ---
    k_sizes<<<(NNODES * 16 + blk - 1) / blk, blk, 0, stream>>>(um, im, sizes);

    // --- scans ---
    k_scan1<<<scan_blocks, 256, 0, stream>>>(deg, sums, dinv, NNODES);
    k_scan2<<<1, 1024, 0, stream>>>(sums, scan_blocks);
    k_scan3<<<(NNODES + blk - 1) / blk, blk, 0, stream>>>(deg, sums, row_ptr, nextp, nnz);

    // --- FAT2: scatterX(ILP-8) || mark-pass1 ---
    k_fat2<<<nst * 2 * 8, blk, 0, stream>>>(rows, cols, nextp, pcol, flag2, nnz);

    // --- mark pass2 (+ per-block flag2 counts), standalone ---
    k_pass2<<<chunks + scan_blocks, blk, 0, stream>>>(rows, cols, flag2, flag1,
                                                      cnt2, nnz, chunks);

    // --- worklist compaction: count flag1, dual scan, ballot-rank fill ---
    k_cnt1<<<scan_blocks, blk, 0, stream>>>(flag1, cnt1);
    k_scan_dual<<<1, 1024, 0, stream>>>(cnt1, cnt2, scan_blocks, wcnt, wcnt + 1);
    k_fill<<<scan_blocks, blk, 0, stream>>>(flag1, flag2, cnt1, cnt2, wl1, wl2);

    int n_full = NNODES * 8;
    int n_samp = 3 * B * 8;

    // layer 1 over wl1 (dense sorted waves)
    k_spmm1<<<(n_full + blk - 1) / blk, blk, 0, stream>>>(row_ptr, pcol, dinv, sizes,
                                                          wl1, wcnt,
                                                          ue, ie, (unsigned*)Y1);
    // layer 2 over wl2 (dense sorted waves)
    k_spmm2<<<(n_full + blk - 1) / blk, blk, 0, stream>>>(row_ptr, pcol, dinv,
                                                          wl2, wcnt + 1,
                                                          (const unsigned*)Y1, (unsigned*)X2);
    // layer 3: sampled rows, fused epilogue + ego
    k_spmm3<<<(n_samp + blk - 1) / blk, blk, 0, stream>>>(row_ptr, pcol, dinv, sizes,
                                                          ue, ie,
                                                          (const unsigned*)Y1,
                                                          (const unsigned*)X2,
                                                          users, pos, neg, out);
}

// Round 12
// 236.777 us; speedup vs baseline: 1.1073x; 1.1073x over previous
//
#include <hip/hip_runtime.h>

#define N_USERS 400000
#define N_ITEMS 200000
#define NNODES  600000   // N_USERS + N_ITEMS
#define D 64
#define B 8192
#define NBKT 8

typedef int v4i __attribute__((ext_vector_type(4)));

// ---------------------------------------------------------------------------
// bf16 helpers
// ---------------------------------------------------------------------------
__device__ __forceinline__ float bflo(unsigned u) { return __uint_as_float(u << 16); }
__device__ __forceinline__ float bfhi(unsigned u) { return __uint_as_float(u & 0xffff0000u); }
__device__ __forceinline__ unsigned f2bf(float f) {   // round-to-nearest-even
    unsigned u = __float_as_uint(f);
    unsigned r = u + 0x7fffu + ((u >> 16) & 1u);
    return r >> 16;
}

// acc[0..7] += v * bf16x8(word4)
__device__ __forceinline__ void unpack_fma(float* acc, uint4 wv, float v) {
    acc[0] += v * bflo(wv.x); acc[1] += v * bfhi(wv.x);
    acc[2] += v * bflo(wv.y); acc[3] += v * bfhi(wv.y);
    acc[4] += v * bflo(wv.z); acc[5] += v * bfhi(wv.z);
    acc[6] += v * bflo(wv.w); acc[7] += v * bfhi(wv.w);
}

// Bucket map balanced by expected edge count.
__device__ __forceinline__ int bucket_of(int r) {
    return (r < N_USERS) ? (r / 100000) : (4 + (r - N_USERS) / 50000);
}

// ---------------------------------------------------------------------------
// scans
// ---------------------------------------------------------------------------
__global__ void k_scan1(int* __restrict__ deg, int* __restrict__ sums,
                        float* __restrict__ dinv, int n) {
    __shared__ int lds[256];
    int i = blockIdx.x * 256 + threadIdx.x;
    int v = (i < n) ? deg[i] : 0;
    if (i < n) dinv[i] = (v > 0) ? (float)(1.0 / sqrt((double)v)) : 0.0f;
    lds[threadIdx.x] = v;
    __syncthreads();
    for (int off = 1; off < 256; off <<= 1) {
        int t = (threadIdx.x >= off) ? lds[threadIdx.x - off] : 0;
        __syncthreads();
        lds[threadIdx.x] += t;
        __syncthreads();
    }
    int inc = lds[threadIdx.x];
    if (i < n) deg[i] = inc - v;
    if (threadIdx.x == 255) sums[blockIdx.x] = inc;
}

__global__ void k_scan2(int* __restrict__ sums, int n) {
    __shared__ int lds[1024];
    __shared__ int carry;
    if (threadIdx.x == 0) carry = 0;
    __syncthreads();
    for (int base = 0; base < n; base += 1024) {
        int i = base + threadIdx.x;
        int v = (i < n) ? sums[i] : 0;
        lds[threadIdx.x] = v;
        __syncthreads();
        for (int off = 1; off < 1024; off <<= 1) {
            int t = (threadIdx.x >= off) ? lds[threadIdx.x - off] : 0;
            __syncthreads();
            lds[threadIdx.x] += t;
            __syncthreads();
        }
        int inc = lds[threadIdx.x];
        if (i < n) sums[i] = (inc - v) + carry;
        __syncthreads();
        if (threadIdx.x == 1023) carry += lds[1023];
        __syncthreads();
    }
}

__global__ void k_scan3(const int* __restrict__ deg, const int* __restrict__ sums,
                        int* __restrict__ row_ptr, int* __restrict__ nextp, int nnz) {
    int i = blockIdx.x * blockDim.x + threadIdx.x;
    if (i >= NNODES) return;
    int rp = deg[i] + sums[i >> 8];
    row_ptr[i] = rp;
    nextp[i] = rp;
    if (i == 0) row_ptr[NNODES] = nnz;
}

// ---------------------------------------------------------------------------
// FAT1 (R7 structure, 234us baseline): histX || sizes || seed.
// NEW: sizes role uses NON-TEMPORAL loads (nt flag, no L2 fill) so the
// 153.6MB mask stream stops evicting the deg atomic lines (R7's 42MB
// WRITE_SIZE thrash signature), + ILP-2 (8 lanes/row x 2 int4).
// bid=(g<<3)|x; g=st*13+slot. slot0..7: hist chunk st*8+slot, bucket filter x
// (non-ILP - R9 showed ILP-8 hist hurts occupancy). slot8..11: sizes.
// slot12: seed.
// ---------------------------------------------------------------------------
__global__ void k_fat1(const int* __restrict__ rows,
                       const int* __restrict__ um, const int* __restrict__ im,
                       int* __restrict__ sizes, int* __restrict__ deg,
                       const int* __restrict__ users, const int* __restrict__ pos,
                       const int* __restrict__ neg,
                       char* __restrict__ flag1, char* __restrict__ flag2, int nnz) {
    int bid = blockIdx.x;
    int x = bid & 7;
    int g = bid >> 3;
    int st = g / 13;
    int slot = g - st * 13;
    int t = threadIdx.x;
    if (slot < 8) {
        int e = (st * 8 + slot) * 256 + t;
        if (e >= nnz) return;
        int r = rows[e];
        if (bucket_of(r) == x) atomicAdd(&deg[r], 1);
    } else if (slot < 12) {
        int sb = (st * 4 + (slot - 8)) * 8 + x;
        int r = sb * 32 + (t >> 3);
        int q = t & 7;
        if (r >= NNODES) return;
        const v4i* p = (const v4i*)((r < N_USERS) ? um + (size_t)r * D
                                                  : im + (size_t)(r - N_USERS) * D);
        v4i v0 = __builtin_nontemporal_load(p + q);        // first half of row
        v4i v1 = __builtin_nontemporal_load(p + 8 + q);    // second half
        int s = v0[0] + v0[1] + v0[2] + v0[3] + v1[0] + v1[1] + v1[2] + v1[3];
        s += __shfl_xor(s, 1);
        s += __shfl_xor(s, 2);
        s += __shfl_xor(s, 4);
        if (q == 0) sizes[r] = s;
    } else {
        int slot2 = (st * 8 + x) * 256 + t;
        if (slot2 >= 3 * B) return;
        int set = slot2 / B;
        int b = slot2 - set * B;
        int r;
        if (set == 0)      r = users[b];
        else if (set == 1) r = N_USERS + pos[b];
        else               r = N_USERS + neg[b];
        flag2[r] = 1;
        flag1[r] = 1;
    }
}

// ---------------------------------------------------------------------------
// FAT-B (R7/R8 exact, 57.6us measured): XCD-filtered scatter || mark-pass1.
// Non-ILP (R10 showed ILP-8 scatter regresses: VGPR/occupancy + the 8x
// redundant read stream evicts the pcol L2 window).
// pass1 race: monotone 0->1, benign superset.
// ---------------------------------------------------------------------------
__global__ void k_fatB(const int* __restrict__ rows, const int* __restrict__ cols,
                       int* __restrict__ nextp, int* __restrict__ pcol,
                       char* __restrict__ flag2, int nnz) {
    int bid = blockIdx.x;
    int x = bid & 7;
    int g = bid >> 3;
    int st = g / 9;
    int slot = g - st * 9;
    int t = threadIdx.x;
    if (slot < 8) {
        int e = (st * 8 + slot) * 256 + t;
        if (e >= nnz) return;
        int r = rows[e];
        if (bucket_of(r) != x) return;
        int p = atomicAdd(&nextp[r], 1);
        pcol[p] = cols[e];
    } else {
        int e = (st * 8 + x) * 256 + t;
        if (e >= nnz) return;
        if (flag2[rows[e]]) flag2[cols[e]] = 1;
    }
}

// ---------------------------------------------------------------------------
// COO mark pass2 + per-block flag2 counts. Standalone (no stream sharing).
// NEW: edge blocks ILP-4 (batch 4 rows/cols loads -> 4 independent
// load->load->store chains per lane; was 1).
// ---------------------------------------------------------------------------
__global__ void k_pass2(const int* __restrict__ rows, const int* __restrict__ cols,
                        const char* __restrict__ flag2, char* __restrict__ flag1,
                        int* __restrict__ cnt2, int nnz, int eb) {
    int bid = blockIdx.x;
    int t = threadIdx.x;
    if (bid < eb) {
        int base = bid * 1024 + t;
        int r4[4], c4[4];
        #pragma unroll
        for (int k = 0; k < 4; ++k) {
            int e = base + k * 256;
            r4[k] = (e < nnz) ? rows[e] : -1;
            c4[k] = (e < nnz) ? cols[e] : 0;
        }
        char f4[4];
        #pragma unroll
        for (int k = 0; k < 4; ++k) f4[k] = (r4[k] >= 0) ? flag2[r4[k]] : (char)0;
        #pragma unroll
        for (int k = 0; k < 4; ++k) if (f4[k]) flag1[c4[k]] = 1;
        return;
    }
    int tb = bid - eb;
    int r = tb * 256 + t;
    char f = (r < NNODES) ? flag2[r] : 0;
    if (f) flag1[r] = 1;
    unsigned long long bal = __ballot(f != 0);
    __shared__ int ws[4];
    int lane = t & 63, wv = t >> 6;
    if (lane == 0) ws[wv] = (int)__popcll(bal);
    __syncthreads();
    if (t == 0) cnt2[tb] = ws[0] + ws[1] + ws[2] + ws[3];
}

// per-block flag1 counts (flag1 stable after pass2)
__global__ void k_cnt1(const char* __restrict__ flag1, int* __restrict__ cnt1) {
    int tb = blockIdx.x;
    int t = threadIdx.x;
    int r = tb * 256 + t;
    char f = (r < NNODES) ? flag1[r] : 0;
    unsigned long long bal = __ballot(f != 0);
    __shared__ int ws[4];
    int lane = t & 63, wv = t >> 6;
    if (lane == 0) ws[wv] = (int)__popcll(bal);
    __syncthreads();
    if (t == 0) cnt1[tb] = ws[0] + ws[1] + ws[2] + ws[3];
}

// single-block exclusive scan of TWO count arrays (in place) + totals
__global__ void k_scan_dual(int* __restrict__ a, int* __restrict__ b, int n,
                            int* __restrict__ totA, int* __restrict__ totB) {
    __shared__ int lds[1024];
    __shared__ int carry;
    for (int pass = 0; pass < 2; ++pass) {
        int* arr = pass ? b : a;
        if (threadIdx.x == 0) carry = 0;
        __syncthreads();
        for (int base = 0; base < n; base += 1024) {
            int i = base + threadIdx.x;
            int v = (i < n) ? arr[i] : 0;
            lds[threadIdx.x] = v;
            __syncthreads();
            for (int off = 1; off < 1024; off <<= 1) {
                int t = (threadIdx.x >= off) ? lds[threadIdx.x - off] : 0;
                __syncthreads();
                lds[threadIdx.x] += t;
                __syncthreads();
            }
            int inc = lds[threadIdx.x];
            if (i < n) arr[i] = (inc - v) + carry;
            __syncthreads();
            if (threadIdx.x == 1023) carry += lds[1023];
            __syncthreads();
        }
        if (threadIdx.x == 0) { if (pass) *totB = carry; else *totA = carry; }
        __syncthreads();
    }
}

// ballot-rank fill of both worklists (sorted order -> pcol/y1 locality)
__global__ void k_fill(const char* __restrict__ flag1, const char* __restrict__ flag2,
                       const int* __restrict__ cnt1, const int* __restrict__ cnt2,
                       int* __restrict__ wl1, int* __restrict__ wl2) {
    int tb = blockIdx.x;
    int t = threadIdx.x;
    int r = tb * 256 + t;
    bool a = (r < NNODES) && flag1[r];
    bool b = (r < NNODES) && flag2[r];
    int lane = t & 63, wv = t >> 6;
    unsigned long long lt = (1ull << lane) - 1ull;
    unsigned long long ba = __ballot(a);
    unsigned long long bb = __ballot(b);
    __shared__ int wa[4], wb[4];
    if (lane == 0) { wa[wv] = (int)__popcll(ba); wb[wv] = (int)__popcll(bb); }
    __syncthreads();
    int offA = 0, offB = 0;
    for (int i = 0; i < wv; ++i) { offA += wa[i]; offB += wb[i]; }
    if (a) wl1[cnt1[tb] + offA + (int)__popcll(ba & lt)] = r;
    if (b) wl2[cnt2[tb] + offB + (int)__popcll(bb & lt)] = r;
}

// ---------------------------------------------------------------------------
// Layer-1 SPMM over the wl1 worklist (dense waves). 8 threads/row, unroll x2.
// ---------------------------------------------------------------------------
__global__ void k_spmm1(const int* __restrict__ row_ptr, const int* __restrict__ pcol,
                        const float* __restrict__ dinv, const int* __restrict__ sizes,
                        const int* __restrict__ wl1, const int* __restrict__ wl1_cnt,
                        const float* __restrict__ ue, const float* __restrict__ ie,
                        unsigned* __restrict__ y1) {
    int tid = blockIdx.x * blockDim.x + threadIdx.x;
    int w = tid >> 3;
    if (w >= *wl1_cnt) return;
    int r = wl1[w];
    int c8 = (tid & 7) << 3;          // f32 col base
    int s = row_ptr[r];
    int e = row_ptr[r + 1];
    float dr = dinv[r];
    float acc[8] = {0.f, 0.f, 0.f, 0.f, 0.f, 0.f, 0.f, 0.f};
    int i = s;
    for (; i + 1 < e; i += 2) {
        int c0 = pcol[i], c1 = pcol[i + 1];
        float v0 = dr * dinv[c0], v1 = dr * dinv[c1];
        int sz0 = sizes[c0], sz1 = sizes[c1];
        const float* p0 = ((c0 < N_USERS) ? ue + (size_t)c0 * D
                                          : ie + (size_t)(c0 - N_USERS) * D) + c8;
        const float* p1 = ((c1 < N_USERS) ? ue + (size_t)c1 * D
                                          : ie + (size_t)(c1 - N_USERS) * D) + c8;
        float4 a0 = *(const float4*)p0;
        float4 a1 = *(const float4*)(p0 + 4);
        float4 b0 = *(const float4*)p1;
        float4 b1 = *(const float4*)(p1 + 4);
        acc[0] += v0 * ((c8 + 0 < sz0) ? a0.x : 0.f) + v1 * ((c8 + 0 < sz1) ? b0.x : 0.f);
        acc[1] += v0 * ((c8 + 1 < sz0) ? a0.y : 0.f) + v1 * ((c8 + 1 < sz1) ? b0.y : 0.f);
        acc[2] += v0 * ((c8 + 2 < sz0) ? a0.z : 0.f) + v1 * ((c8 + 2 < sz1) ? b0.z : 0.f);
        acc[3] += v0 * ((c8 + 3 < sz0) ? a0.w : 0.f) + v1 * ((c8 + 3 < sz1) ? b0.w : 0.f);
        acc[4] += v0 * ((c8 + 4 < sz0) ? a1.x : 0.f) + v1 * ((c8 + 4 < sz1) ? b1.x : 0.f);
        acc[5] += v0 * ((c8 + 5 < sz0) ? a1.y : 0.f) + v1 * ((c8 + 5 < sz1) ? b1.y : 0.f);
        acc[6] += v0 * ((c8 + 6 < sz0) ? a1.z : 0.f) + v1 * ((c8 + 6 < sz1) ? b1.z : 0.f);
        acc[7] += v0 * ((c8 + 7 < sz0) ? a1.w : 0.f) + v1 * ((c8 + 7 < sz1) ? b1.w : 0.f);
    }
    if (i < e) {
        int c = pcol[i];
        float v = dr * dinv[c];
        int sz = sizes[c];
        const float* p = ((c < N_USERS) ? ue + (size_t)c * D
                                        : ie + (size_t)(c - N_USERS) * D) + c8;
        float4 e0 = *(const float4*)p;
        float4 e1 = *(const float4*)(p + 4);
        acc[0] += v * ((c8 + 0 < sz) ? e0.x : 0.f);
        acc[1] += v * ((c8 + 1 < sz) ? e0.y : 0.f);
        acc[2] += v * ((c8 + 2 < sz) ? e0.z : 0.f);
        acc[3] += v * ((c8 + 3 < sz) ? e0.w : 0.f);
        acc[4] += v * ((c8 + 4 < sz) ? e1.x : 0.f);
        acc[5] += v * ((c8 + 5 < sz) ? e1.y : 0.f);
        acc[6] += v * ((c8 + 6 < sz) ? e1.z : 0.f);
        acc[7] += v * ((c8 + 7 < sz) ? e1.w : 0.f);
    }
    uint4 o;
    o.x = f2bf(acc[0]) | (f2bf(acc[1]) << 16);
    o.y = f2bf(acc[2]) | (f2bf(acc[3]) << 16);
    o.z = f2bf(acc[4]) | (f2bf(acc[5]) << 16);
    o.w = f2bf(acc[6]) | (f2bf(acc[7]) << 16);
    *(uint4*)(y1 + (size_t)r * 32 + (tid & 7) * 4) = o;
}

// ---------------------------------------------------------------------------
// Layer-2 bf16 SPMM over the wl2 worklist: x2[r] = sum val * y1[col].
// ---------------------------------------------------------------------------
__global__ void k_spmm2(const int* __restrict__ row_ptr, const int* __restrict__ pcol,
                        const float* __restrict__ dinv,
                        const int* __restrict__ wl2, const int* __restrict__ wl2_cnt,
                        const unsigned* __restrict__ y1, unsigned* __restrict__ x2) {
    int tid = blockIdx.x * blockDim.x + threadIdx.x;
    int w = tid >> 3;
    if (w >= *wl2_cnt) return;
    int r = wl2[w];
    int cp = (tid & 7) << 2;
    int s = row_ptr[r];
    int e = row_ptr[r + 1];
    float dr = dinv[r];
    float acc[8] = {0.f, 0.f, 0.f, 0.f, 0.f, 0.f, 0.f, 0.f};
    int i = s;
    for (; i + 1 < e; i += 2) {
        int c0 = pcol[i], c1 = pcol[i + 1];
        float v0 = dr * dinv[c0], v1 = dr * dinv[c1];
        uint4 w0 = *(const uint4*)(y1 + (size_t)c0 * 32 + cp);
        uint4 w1 = *(const uint4*)(y1 + (size_t)c1 * 32 + cp);
        unpack_fma(acc, w0, v0);
        unpack_fma(acc, w1, v1);
    }
    if (i < e) {
        int c0 = pcol[i];
        float v0 = dr * dinv[c0];
        uint4 w0 = *(const uint4*)(y1 + (size_t)c0 * 32 + cp);
        unpack_fma(acc, w0, v0);
    }
    uint4 o;
    o.x = f2bf(acc[0]) | (f2bf(acc[1]) << 16);
    o.y = f2bf(acc[2]) | (f2bf(acc[3]) << 16);
    o.z = f2bf(acc[4]) | (f2bf(acc[5]) << 16);
    o.w = f2bf(acc[6]) | (f2bf(acc[7]) << 16);
    *(uint4*)(x2 + (size_t)r * 32 + cp) = o;
}

// ---------------------------------------------------------------------------
// Final sampled layer, fused epilogue + ego.
// ---------------------------------------------------------------------------
__global__ void k_spmm3(const int* __restrict__ row_ptr, const int* __restrict__ pcol,
                        const float* __restrict__ dinv, const int* __restrict__ sizes,
                        const float* __restrict__ ue, const float* __restrict__ ie,
                        const unsigned* __restrict__ y1, const unsigned* __restrict__ x2,
                        const int* __restrict__ users, const int* __restrict__ pos,
                        const int* __restrict__ neg, float* __restrict__ out) {
    int tid = blockIdx.x * blockDim.x + threadIdx.x;
    int slot = tid >> 3;
    if (slot >= 3 * B) return;
    int cp = (tid & 7) << 2;          // uint base
    int c8 = (tid & 7) << 3;          // f32 col base
    int set = slot / B;
    int b = slot - set * B;
    int r;
    if (set == 0)      r = users[b];
    else if (set == 1) r = N_USERS + pos[b];
    else               r = N_USERS + neg[b];
    int s = row_ptr[r];
    int e = row_ptr[r + 1];
    float dr = dinv[r];
    float acc[8] = {0.f, 0.f, 0.f, 0.f, 0.f, 0.f, 0.f, 0.f};
    uint4 g1 = *(const uint4*)(y1 + (size_t)r * 32 + cp);
    uint4 g2 = *(const uint4*)(x2 + (size_t)r * 32 + cp);
    unpack_fma(acc, g1, 1.0f);
    unpack_fma(acc, g2, 1.0f);
    int i = s;
    for (; i + 1 < e; i += 2) {
        int c0 = pcol[i], c1 = pcol[i + 1];
        float v0 = dr * dinv[c0], v1 = dr * dinv[c1];
        uint4 w0 = *(const uint4*)(x2 + (size_t)c0 * 32 + cp);
        uint4 w1 = *(const uint4*)(x2 + (size_t)c1 * 32 + cp);
        unpack_fma(acc, w0, v0);
        unpack_fma(acc, w1, v1);
    }
    if (i < e) {
        int c0 = pcol[i];
        float v0 = dr * dinv[c0];
        uint4 w0 = *(const uint4*)(x2 + (size_t)c0 * 32 + cp);
        unpack_fma(acc, w0, v0);
    }
    const float* p = ((r < N_USERS) ? ue + (size_t)r * D
                                    : ie + (size_t)(r - N_USERS) * D) + c8;
    float4 e0 = *(const float4*)p;
    float4 e1 = *(const float4*)(p + 4);
    int sz = sizes[r];
    e0.x = (c8 + 0 < sz) ? e0.x : 0.f; e0.y = (c8 + 1 < sz) ? e0.y : 0.f;
    e0.z = (c8 + 2 < sz) ? e0.z : 0.f; e0.w = (c8 + 3 < sz) ? e0.w : 0.f;
    e1.x = (c8 + 4 < sz) ? e1.x : 0.f; e1.y = (c8 + 5 < sz) ? e1.y : 0.f;
    e1.z = (c8 + 6 < sz) ? e1.z : 0.f; e1.w = (c8 + 7 < sz) ? e1.w : 0.f;
    float4 oa, ob;
    oa.x = (e0.x + acc[0]) * 0.25f; oa.y = (e0.y + acc[1]) * 0.25f;
    oa.z = (e0.z + acc[2]) * 0.25f; oa.w = (e0.w + acc[3]) * 0.25f;
    ob.x = (e1.x + acc[4]) * 0.25f; ob.y = (e1.y + acc[5]) * 0.25f;
    ob.z = (e1.z + acc[6]) * 0.25f; ob.w = (e1.w + acc[7]) * 0.25f;
    float* o0 = out + (size_t)slot * D + c8;
    float* o1 = out + (size_t)(3 * B + slot) * D + c8;
    *(float4*)o0 = oa; *(float4*)(o0 + 4) = ob;
    *(float4*)o1 = e0; *(float4*)(o1 + 4) = e1;
}

extern "C" void kernel_launch(void* const* d_in, const int* in_sizes, int n_in,
                              void* d_out, int out_size, void* d_ws, size_t ws_size,
                              hipStream_t stream) {
    const float* ue   = (const float*)d_in[0];
    const float* ie   = (const float*)d_in[1];
    const int*   um   = (const int*)d_in[2];
    const int*   im   = (const int*)d_in[3];
    const int*   rows = (const int*)d_in[4];
    const int*   cols = (const int*)d_in[5];
    const int*   users = (const int*)d_in[7];
    const int*   pos   = (const int*)d_in[8];
    const int*   neg   = (const int*)d_in[9];
    int nnz = in_sizes[4];

    float* out = (float*)d_out;

    // workspace layout (16B-aligned bf16 node buffers first)
    unsigned short* Y1 = (unsigned short*)d_ws;         // NNODES*D bf16
    unsigned short* X2 = Y1 + (size_t)NNODES * D;       // NNODES*D bf16
    int*   deg     = (int*)(X2 + (size_t)NNODES * D);   // NNODES
    int*   row_ptr = deg + NNODES;                      // NNODES+1
    int*   nextp   = row_ptr + NNODES + 1;              // NNODES
    int*   sizes   = nextp + NNODES;                    // NNODES
    int*   sums    = sizes + NNODES;                    // up to 4096
    int*   wcnt    = sums + 4096;                       // [0]=wl1_cnt [1]=wl2_cnt
    int*   cnt1    = wcnt + 16;                         // 2344 (+pad)
    int*   cnt2    = cnt1 + 2360;                       // 2344 (+pad)
    float* dinv    = (float*)(cnt2 + 2360);             // NNODES
    int*   pcol    = (int*)(dinv + NNODES);             // nnz
    char*  flag1   = (char*)(pcol + nnz);               // NNODES
    char*  flag2   = flag1 + NNODES;                    // NNODES
    int*   wl1     = (int*)(((uintptr_t)(flag2 + NNODES) + 15) & ~(uintptr_t)15);
    int*   wl2     = wl1 + NNODES;

    const int blk = 256;
    const int scan_blocks = (NNODES + 255) / 256;       // 2344
    int chunks = (nnz + 255) / 256;                     // 4688
    int nst = (chunks + 7) / 8;                         // 586 supertiles
    // sizes coverage: nst*4*8 = 18752 >= 18750 ILP-2 blocks needed

    hipMemsetAsync(deg, 0, (size_t)NNODES * sizeof(int), stream);
    hipMemsetAsync(flag1, 0, (size_t)2 * NNODES, stream);

    // --- FAT1: histX || sizes(nt, ILP-2) || seed ---
    k_fat1<<<nst * 13 * 8, blk, 0, stream>>>(rows, um, im, sizes, deg,
                                             users, pos, neg, flag1, flag2, nnz);

    // --- scans ---
    k_scan1<<<scan_blocks, 256, 0, stream>>>(deg, sums, dinv, NNODES);
    k_scan2<<<1, 1024, 0, stream>>>(sums, scan_blocks);
    k_scan3<<<(NNODES + blk - 1) / blk, blk, 0, stream>>>(deg, sums, row_ptr, nextp, nnz);

    // --- FAT-B: scatterX || mark-pass1 (R7/R8 exact) ---
    k_fatB<<<nst * 9 * 8, blk, 0, stream>>>(rows, cols, nextp, pcol, flag2, nnz);

    // --- mark pass2 (ILP-4 edge blocks) + per-block flag2 counts ---
    {
        int eb = (nnz + 1023) / 1024;                   // 1172
        k_pass2<<<eb + scan_blocks, blk, 0, stream>>>(rows, cols, flag2, flag1,
                                                      cnt2, nnz, eb);
    }

    // --- worklist compaction: count flag1, dual scan, ballot-rank fill ---
    k_cnt1<<<scan_blocks, blk, 0, stream>>>(flag1, cnt1);
    k_scan_dual<<<1, 1024, 0, stream>>>(cnt1, cnt2, scan_blocks, wcnt, wcnt + 1);
    k_fill<<<scan_blocks, blk, 0, stream>>>(flag1, flag2, cnt1, cnt2, wl1, wl2);

    int n_full = NNODES * 8;
    int n_samp = 3 * B * 8;

    // layer 1 over wl1 (dense sorted waves)
    k_spmm1<<<(n_full + blk - 1) / blk, blk, 0, stream>>>(row_ptr, pcol, dinv, sizes,
                                                          wl1, wcnt,
                                                          ue, ie, (unsigned*)Y1);
    // layer 2 over wl2 (dense sorted waves)
    k_spmm2<<<(n_full + blk - 1) / blk, blk, 0, stream>>>(row_ptr, pcol, dinv,
                                                          wl2, wcnt + 1,
                                                          (const unsigned*)Y1, (unsigned*)X2);
    // layer 3: sampled rows, fused epilogue + ego
    k_spmm3<<<(n_samp + blk - 1) / blk, blk, 0, stream>>>(row_ptr, pcol, dinv, sizes,
                                                          ue, ie,
                                                          (const unsigned*)Y1,
                                                          (const unsigned*)X2,
                                                          users, pos, neg, out);
}

// Round 13
// 215.569 us; speedup vs baseline: 1.2163x; 1.0984x over previous
//
#include <hip/hip_runtime.h>

#define N_USERS 400000
#define N_ITEMS 200000
#define NNODES  600000   // N_USERS + N_ITEMS
#define D 64
#define B 8192
#define NBKT 8

typedef int v4i __attribute__((ext_vector_type(4)));

// ---------------------------------------------------------------------------
// bf16 helpers
// ---------------------------------------------------------------------------
__device__ __forceinline__ float bflo(unsigned u) { return __uint_as_float(u << 16); }
__device__ __forceinline__ float bfhi(unsigned u) { return __uint_as_float(u & 0xffff0000u); }
__device__ __forceinline__ unsigned f2bf(float f) {   // round-to-nearest-even
    unsigned u = __float_as_uint(f);
    unsigned r = u + 0x7fffu + ((u >> 16) & 1u);
    return r >> 16;
}

// acc[0..7] += v * bf16x8(word4)
__device__ __forceinline__ void unpack_fma(float* acc, uint4 wv, float v) {
    acc[0] += v * bflo(wv.x); acc[1] += v * bfhi(wv.x);
    acc[2] += v * bflo(wv.y); acc[3] += v * bfhi(wv.y);
    acc[4] += v * bflo(wv.z); acc[5] += v * bfhi(wv.z);
    acc[6] += v * bflo(wv.w); acc[7] += v * bfhi(wv.w);
}

// Bucket map balanced by expected edge count.
__device__ __forceinline__ int bucket_of(int r) {
    return (r < N_USERS) ? (r / 100000) : (4 + (r - N_USERS) / 50000);
}

// ---------------------------------------------------------------------------
// K1: XCD-filtered hist that ALSO records rank[e] = old count (the atomic's
// return value, previously discarded). This converts the later scatter into
// a deterministic, atomic-free placement. Runs with a QUIET L2 (no mask
// stream): R7/R12 showed the stream evicts deg atomic lines (42MB WRITE
// thrash); nt-load hints don't engage on gfx950 (R12: identical counters).
// bid < nhist: chunk bid>>3, bucket filter x=bid&7 (XCD-local atomics).
// else: sample-seed tail blocks.
// Accepted cost: rank lines are committed by 8 XCD-blocks each -> partial
// line writeback amp (~30MB, fire-and-forget).
// ---------------------------------------------------------------------------
__global__ void k_hrs(const int* __restrict__ rows, int* __restrict__ deg,
                      int* __restrict__ rank,
                      const int* __restrict__ users, const int* __restrict__ pos,
                      const int* __restrict__ neg,
                      char* __restrict__ flag1, char* __restrict__ flag2,
                      int nnz, int nhist) {
    int bid = blockIdx.x;
    int t = threadIdx.x;
    if (bid < nhist) {
        int x = bid & 7;
        int e = (bid >> 3) * 256 + t;
        if (e >= nnz) return;
        int r = rows[e];
        if (bucket_of(r) == x) rank[e] = atomicAdd(&deg[r], 1);
    } else {
        int slot2 = (bid - nhist) * 256 + t;
        if (slot2 >= 3 * B) return;
        int set = slot2 / B;
        int b = slot2 - set * B;
        int r;
        if (set == 0)      r = users[b];
        else if (set == 1) r = N_USERS + pos[b];
        else               r = N_USERS + neg[b];
        flag2[r] = 1;
        flag1[r] = 1;
    }
}

// ---------------------------------------------------------------------------
// scans
// ---------------------------------------------------------------------------
__global__ void k_scan1(int* __restrict__ deg, int* __restrict__ sums,
                        float* __restrict__ dinv, int n) {
    __shared__ int lds[256];
    int i = blockIdx.x * 256 + threadIdx.x;
    int v = (i < n) ? deg[i] : 0;
    if (i < n) dinv[i] = (v > 0) ? (float)(1.0 / sqrt((double)v)) : 0.0f;
    lds[threadIdx.x] = v;
    __syncthreads();
    for (int off = 1; off < 256; off <<= 1) {
        int t = (threadIdx.x >= off) ? lds[threadIdx.x - off] : 0;
        __syncthreads();
        lds[threadIdx.x] += t;
        __syncthreads();
    }
    int inc = lds[threadIdx.x];
    if (i < n) deg[i] = inc - v;
    if (threadIdx.x == 255) sums[blockIdx.x] = inc;
}

__global__ void k_scan2(int* __restrict__ sums, int n) {
    __shared__ int lds[1024];
    __shared__ int carry;
    if (threadIdx.x == 0) carry = 0;
    __syncthreads();
    for (int base = 0; base < n; base += 1024) {
        int i = base + threadIdx.x;
        int v = (i < n) ? sums[i] : 0;
        lds[threadIdx.x] = v;
        __syncthreads();
        for (int off = 1; off < 1024; off <<= 1) {
            int t = (threadIdx.x >= off) ? lds[threadIdx.x - off] : 0;
            __syncthreads();
            lds[threadIdx.x] += t;
            __syncthreads();
        }
        int inc = lds[threadIdx.x];
        if (i < n) sums[i] = (inc - v) + carry;
        __syncthreads();
        if (threadIdx.x == 1023) carry += lds[1023];
        __syncthreads();
    }
}

// scan3 + COO mark-pass1 tail (pass1 runs after K1's seed; light blocks, no
// stream co-residency -- R8's fatC lesson). pass1 race: monotone 0->1,
// benign superset.
__global__ void k_scan3p1(const int* __restrict__ deg, const int* __restrict__ sums,
                          int* __restrict__ row_ptr,
                          const int* __restrict__ rows, const int* __restrict__ cols,
                          char* __restrict__ flag2, int nnz, int scan_blocks) {
    int bid = blockIdx.x;
    int t = threadIdx.x;
    if (bid < scan_blocks) {
        int i = bid * 256 + t;
        if (i >= NNODES) return;
        row_ptr[i] = deg[i] + sums[i >> 8];
        if (i == 0) row_ptr[NNODES] = nnz;
    } else {
        int e = (bid - scan_blocks) * 256 + t;
        if (e >= nnz) return;
        if (flag2[rows[e]]) flag2[cols[e]] = 1;
    }
}

// ---------------------------------------------------------------------------
// K2: deterministic scatter (NO atomics: pcol[row_ptr[r]+rank[e]] = cols[e])
// || mask-popcount stream (ILP-2). The scatter is store-only after two loads
// -- fire-and-forget stores tolerate the stream's L2 thrash, unlike the old
// atomic-return chain (R8: 57us @ VALUBusy 5.9%). Bucket filter keeps each
// XCD's pcol stores in a ~600KB L2-local window (kills write amp).
// bid=(g<<3)|x; g=st*12+slot. slot0..7: scatter chunk st*8+slot filter x.
// slot8..11: sizes ILP-2 blocks.
// ---------------------------------------------------------------------------
__global__ void k_fatS(const int* __restrict__ rows, const int* __restrict__ cols,
                       const int* __restrict__ rank, const int* __restrict__ row_ptr,
                       int* __restrict__ pcol,
                       const int* __restrict__ um, const int* __restrict__ im,
                       int* __restrict__ sizes, int nnz) {
    int bid = blockIdx.x;
    int x = bid & 7;
    int g = bid >> 3;
    int st = g / 12;
    int slot = g - st * 12;
    int t = threadIdx.x;
    if (slot < 8) {
        int e = (st * 8 + slot) * 256 + t;
        if (e >= nnz) return;
        int r = rows[e];
        if (bucket_of(r) != x) return;
        pcol[row_ptr[r] + rank[e]] = cols[e];
    } else {
        int sb = (st * 4 + (slot - 8)) * 8 + x;
        int r = sb * 32 + (t >> 3);
        int q = t & 7;
        if (r >= NNODES) return;
        const v4i* p = (const v4i*)((r < N_USERS) ? um + (size_t)r * D
                                                  : im + (size_t)(r - N_USERS) * D);
        v4i v0 = __builtin_nontemporal_load(p + q);
        v4i v1 = __builtin_nontemporal_load(p + 8 + q);
        int s = v0[0] + v0[1] + v0[2] + v0[3] + v1[0] + v1[1] + v1[2] + v1[3];
        s += __shfl_xor(s, 1);
        s += __shfl_xor(s, 2);
        s += __shfl_xor(s, 4);
        if (q == 0) sizes[r] = s;
    }
}

// ---------------------------------------------------------------------------
// COO mark pass2 (ILP-4 edge blocks) + per-block flag2 counts. Standalone.
// ---------------------------------------------------------------------------
__global__ void k_pass2(const int* __restrict__ rows, const int* __restrict__ cols,
                        const char* __restrict__ flag2, char* __restrict__ flag1,
                        int* __restrict__ cnt2, int nnz, int eb) {
    int bid = blockIdx.x;
    int t = threadIdx.x;
    if (bid < eb) {
        int base = bid * 1024 + t;
        int r4[4], c4[4];
        #pragma unroll
        for (int k = 0; k < 4; ++k) {
            int e = base + k * 256;
            r4[k] = (e < nnz) ? rows[e] : -1;
            c4[k] = (e < nnz) ? cols[e] : 0;
        }
        char f4[4];
        #pragma unroll
        for (int k = 0; k < 4; ++k) f4[k] = (r4[k] >= 0) ? flag2[r4[k]] : (char)0;
        #pragma unroll
        for (int k = 0; k < 4; ++k) if (f4[k]) flag1[c4[k]] = 1;
        return;
    }
    int tb = bid - eb;
    int r = tb * 256 + t;
    char f = (r < NNODES) ? flag2[r] : 0;
    if (f) flag1[r] = 1;
    unsigned long long bal = __ballot(f != 0);
    __shared__ int ws[4];
    int lane = t & 63, wv = t >> 6;
    if (lane == 0) ws[wv] = (int)__popcll(bal);
    __syncthreads();
    if (t == 0) cnt2[tb] = ws[0] + ws[1] + ws[2] + ws[3];
}

// per-block flag1 counts (flag1 stable after pass2)
__global__ void k_cnt1(const char* __restrict__ flag1, int* __restrict__ cnt1) {
    int tb = blockIdx.x;
    int t = threadIdx.x;
    int r = tb * 256 + t;
    char f = (r < NNODES) ? flag1[r] : 0;
    unsigned long long bal = __ballot(f != 0);
    __shared__ int ws[4];
    int lane = t & 63, wv = t >> 6;
    if (lane == 0) ws[wv] = (int)__popcll(bal);
    __syncthreads();
    if (t == 0) cnt1[tb] = ws[0] + ws[1] + ws[2] + ws[3];
}

// single-block exclusive scan of TWO count arrays (in place) + totals
__global__ void k_scan_dual(int* __restrict__ a, int* __restrict__ b, int n,
                            int* __restrict__ totA, int* __restrict__ totB) {
    __shared__ int lds[1024];
    __shared__ int carry;
    for (int pass = 0; pass < 2; ++pass) {
        int* arr = pass ? b : a;
        if (threadIdx.x == 0) carry = 0;
        __syncthreads();
        for (int base = 0; base < n; base += 1024) {
            int i = base + threadIdx.x;
            int v = (i < n) ? arr[i] : 0;
            lds[threadIdx.x] = v;
            __syncthreads();
            for (int off = 1; off < 1024; off <<= 1) {
                int t = (threadIdx.x >= off) ? lds[threadIdx.x - off] : 0;
                __syncthreads();
                lds[threadIdx.x] += t;
                __syncthreads();
            }
            int inc = lds[threadIdx.x];
            if (i < n) arr[i] = (inc - v) + carry;
            __syncthreads();
            if (threadIdx.x == 1023) carry += lds[1023];
            __syncthreads();
        }
        if (threadIdx.x == 0) { if (pass) *totB = carry; else *totA = carry; }
        __syncthreads();
    }
}

// ballot-rank fill of both worklists (sorted order -> pcol/y1 locality)
__global__ void k_fill(const char* __restrict__ flag1, const char* __restrict__ flag2,
                       const int* __restrict__ cnt1, const int* __restrict__ cnt2,
                       int* __restrict__ wl1, int* __restrict__ wl2) {
    int tb = blockIdx.x;
    int t = threadIdx.x;
    int r = tb * 256 + t;
    bool a = (r < NNODES) && flag1[r];
    bool b = (r < NNODES) && flag2[r];
    int lane = t & 63, wv = t >> 6;
    unsigned long long lt = (1ull << lane) - 1ull;
    unsigned long long ba = __ballot(a);
    unsigned long long bb = __ballot(b);
    __shared__ int wa[4], wb[4];
    if (lane == 0) { wa[wv] = (int)__popcll(ba); wb[wv] = (int)__popcll(bb); }
    __syncthreads();
    int offA = 0, offB = 0;
    for (int i = 0; i < wv; ++i) { offA += wa[i]; offB += wb[i]; }
    if (a) wl1[cnt1[tb] + offA + (int)__popcll(ba & lt)] = r;
    if (b) wl2[cnt2[tb] + offB + (int)__popcll(bb & lt)] = r;
}

// ---------------------------------------------------------------------------
// Layer-1 SPMM over the wl1 worklist (dense waves). 8 threads/row, unroll x2.
// ---------------------------------------------------------------------------
__global__ void k_spmm1(const int* __restrict__ row_ptr, const int* __restrict__ pcol,
                        const float* __restrict__ dinv, const int* __restrict__ sizes,
                        const int* __restrict__ wl1, const int* __restrict__ wl1_cnt,
                        const float* __restrict__ ue, const float* __restrict__ ie,
                        unsigned* __restrict__ y1) {
    int tid = blockIdx.x * blockDim.x + threadIdx.x;
    int w = tid >> 3;
    if (w >= *wl1_cnt) return;
    int r = wl1[w];
    int c8 = (tid & 7) << 3;          // f32 col base
    int s = row_ptr[r];
    int e = row_ptr[r + 1];
    float dr = dinv[r];
    float acc[8] = {0.f, 0.f, 0.f, 0.f, 0.f, 0.f, 0.f, 0.f};
    int i = s;
    for (; i + 1 < e; i += 2) {
        int c0 = pcol[i], c1 = pcol[i + 1];
        float v0 = dr * dinv[c0], v1 = dr * dinv[c1];
        int sz0 = sizes[c0], sz1 = sizes[c1];
        const float* p0 = ((c0 < N_USERS) ? ue + (size_t)c0 * D
                                          : ie + (size_t)(c0 - N_USERS) * D) + c8;
        const float* p1 = ((c1 < N_USERS) ? ue + (size_t)c1 * D
                                          : ie + (size_t)(c1 - N_USERS) * D) + c8;
        float4 a0 = *(const float4*)p0;
        float4 a1 = *(const float4*)(p0 + 4);
        float4 b0 = *(const float4*)p1;
        float4 b1 = *(const float4*)(p1 + 4);
        acc[0] += v0 * ((c8 + 0 < sz0) ? a0.x : 0.f) + v1 * ((c8 + 0 < sz1) ? b0.x : 0.f);
        acc[1] += v0 * ((c8 + 1 < sz0) ? a0.y : 0.f) + v1 * ((c8 + 1 < sz1) ? b0.y : 0.f);
        acc[2] += v0 * ((c8 + 2 < sz0) ? a0.z : 0.f) + v1 * ((c8 + 2 < sz1) ? b0.z : 0.f);
        acc[3] += v0 * ((c8 + 3 < sz0) ? a0.w : 0.f) + v1 * ((c8 + 3 < sz1) ? b0.w : 0.f);
        acc[4] += v0 * ((c8 + 4 < sz0) ? a1.x : 0.f) + v1 * ((c8 + 4 < sz1) ? b1.x : 0.f);
        acc[5] += v0 * ((c8 + 5 < sz0) ? a1.y : 0.f) + v1 * ((c8 + 5 < sz1) ? b1.y : 0.f);
        acc[6] += v0 * ((c8 + 6 < sz0) ? a1.z : 0.f) + v1 * ((c8 + 6 < sz1) ? b1.z : 0.f);
        acc[7] += v0 * ((c8 + 7 < sz0) ? a1.w : 0.f) + v1 * ((c8 + 7 < sz1) ? b1.w : 0.f);
    }
    if (i < e) {
        int c = pcol[i];
        float v = dr * dinv[c];
        int sz = sizes[c];
        const float* p = ((c < N_USERS) ? ue + (size_t)c * D
                                        : ie + (size_t)(c - N_USERS) * D) + c8;
        float4 e0 = *(const float4*)p;
        float4 e1 = *(const float4*)(p + 4);
        acc[0] += v * ((c8 + 0 < sz) ? e0.x : 0.f);
        acc[1] += v * ((c8 + 1 < sz) ? e0.y : 0.f);
        acc[2] += v * ((c8 + 2 < sz) ? e0.z : 0.f);
        acc[3] += v * ((c8 + 3 < sz) ? e0.w : 0.f);
        acc[4] += v * ((c8 + 4 < sz) ? e1.x : 0.f);
        acc[5] += v * ((c8 + 5 < sz) ? e1.y : 0.f);
        acc[6] += v * ((c8 + 6 < sz) ? e1.z : 0.f);
        acc[7] += v * ((c8 + 7 < sz) ? e1.w : 0.f);
    }
    uint4 o;
    o.x = f2bf(acc[0]) | (f2bf(acc[1]) << 16);
    o.y = f2bf(acc[2]) | (f2bf(acc[3]) << 16);
    o.z = f2bf(acc[4]) | (f2bf(acc[5]) << 16);
    o.w = f2bf(acc[6]) | (f2bf(acc[7]) << 16);
    *(uint4*)(y1 + (size_t)r * 32 + (tid & 7) * 4) = o;
}

// ---------------------------------------------------------------------------
// Layer-2 bf16 SPMM over the wl2 worklist: x2[r] = sum val * y1[col].
// ---------------------------------------------------------------------------
__global__ void k_spmm2(const int* __restrict__ row_ptr, const int* __restrict__ pcol,
                        const float* __restrict__ dinv,
                        const int* __restrict__ wl2, const int* __restrict__ wl2_cnt,
                        const unsigned* __restrict__ y1, unsigned* __restrict__ x2) {
    int tid = blockIdx.x * blockDim.x + threadIdx.x;
    int w = tid >> 3;
    if (w >= *wl2_cnt) return;
    int r = wl2[w];
    int cp = (tid & 7) << 2;
    int s = row_ptr[r];
    int e = row_ptr[r + 1];
    float dr = dinv[r];
    float acc[8] = {0.f, 0.f, 0.f, 0.f, 0.f, 0.f, 0.f, 0.f};
    int i = s;
    for (; i + 1 < e; i += 2) {
        int c0 = pcol[i], c1 = pcol[i + 1];
        float v0 = dr * dinv[c0], v1 = dr * dinv[c1];
        uint4 w0 = *(const uint4*)(y1 + (size_t)c0 * 32 + cp);
        uint4 w1 = *(const uint4*)(y1 + (size_t)c1 * 32 + cp);
        unpack_fma(acc, w0, v0);
        unpack_fma(acc, w1, v1);
    }
    if (i < e) {
        int c0 = pcol[i];
        float v0 = dr * dinv[c0];
        uint4 w0 = *(const uint4*)(y1 + (size_t)c0 * 32 + cp);
        unpack_fma(acc, w0, v0);
    }
    uint4 o;
    o.x = f2bf(acc[0]) | (f2bf(acc[1]) << 16);
    o.y = f2bf(acc[2]) | (f2bf(acc[3]) << 16);
    o.z = f2bf(acc[4]) | (f2bf(acc[5]) << 16);
    o.w = f2bf(acc[6]) | (f2bf(acc[7]) << 16);
    *(uint4*)(x2 + (size_t)r * 32 + cp) = o;
}

// ---------------------------------------------------------------------------
// Final sampled layer, fused epilogue + ego.
// ---------------------------------------------------------------------------
__global__ void k_spmm3(const int* __restrict__ row_ptr, const int* __restrict__ pcol,
                        const float* __restrict__ dinv, const int* __restrict__ sizes,
                        const float* __restrict__ ue, const float* __restrict__ ie,
                        const unsigned* __restrict__ y1, const unsigned* __restrict__ x2,
                        const int* __restrict__ users, const int* __restrict__ pos,
                        const int* __restrict__ neg, float* __restrict__ out) {
    int tid = blockIdx.x * blockDim.x + threadIdx.x;
    int slot = tid >> 3;
    if (slot >= 3 * B) return;
    int cp = (tid & 7) << 2;          // uint base
    int c8 = (tid & 7) << 3;          // f32 col base
    int set = slot / B;
    int b = slot - set * B;
    int r;
    if (set == 0)      r = users[b];
    else if (set == 1) r = N_USERS + pos[b];
    else               r = N_USERS + neg[b];
    int s = row_ptr[r];
    int e = row_ptr[r + 1];
    float dr = dinv[r];
    float acc[8] = {0.f, 0.f, 0.f, 0.f, 0.f, 0.f, 0.f, 0.f};
    uint4 g1 = *(const uint4*)(y1 + (size_t)r * 32 + cp);
    uint4 g2 = *(const uint4*)(x2 + (size_t)r * 32 + cp);
    unpack_fma(acc, g1, 1.0f);
    unpack_fma(acc, g2, 1.0f);
    int i = s;
    for (; i + 1 < e; i += 2) {
        int c0 = pcol[i], c1 = pcol[i + 1];
        float v0 = dr * dinv[c0], v1 = dr * dinv[c1];
        uint4 w0 = *(const uint4*)(x2 + (size_t)c0 * 32 + cp);
        uint4 w1 = *(const uint4*)(x2 + (size_t)c1 * 32 + cp);
        unpack_fma(acc, w0, v0);
        unpack_fma(acc, w1, v1);
    }
    if (i < e) {
        int c0 = pcol[i];
        float v0 = dr * dinv[c0];
        uint4 w0 = *(const uint4*)(x2 + (size_t)c0 * 32 + cp);
        unpack_fma(acc, w0, v0);
    }
    const float* p = ((r < N_USERS) ? ue + (size_t)r * D
                                    : ie + (size_t)(r - N_USERS) * D) + c8;
    float4 e0 = *(const float4*)p;
    float4 e1 = *(const float4*)(p + 4);
    int sz = sizes[r];
    e0.x = (c8 + 0 < sz) ? e0.x : 0.f; e0.y = (c8 + 1 < sz) ? e0.y : 0.f;
    e0.z = (c8 + 2 < sz) ? e0.z : 0.f; e0.w = (c8 + 3 < sz) ? e0.w : 0.f;
    e1.x = (c8 + 4 < sz) ? e1.x : 0.f; e1.y = (c8 + 5 < sz) ? e1.y : 0.f;
    e1.z = (c8 + 6 < sz) ? e1.z : 0.f; e1.w = (c8 + 7 < sz) ? e1.w : 0.f;
    float4 oa, ob;
    oa.x = (e0.x + acc[0]) * 0.25f; oa.y = (e0.y + acc[1]) * 0.25f;
    oa.z = (e0.z + acc[2]) * 0.25f; oa.w = (e0.w + acc[3]) * 0.25f;
    ob.x = (e1.x + acc[4]) * 0.25f; ob.y = (e1.y + acc[5]) * 0.25f;
    ob.z = (e1.z + acc[6]) * 0.25f; ob.w = (e1.w + acc[7]) * 0.25f;
    float* o0 = out + (size_t)slot * D + c8;
    float* o1 = out + (size_t)(3 * B + slot) * D + c8;
    *(float4*)o0 = oa; *(float4*)(o0 + 4) = ob;
    *(float4*)o1 = e0; *(float4*)(o1 + 4) = e1;
}

extern "C" void kernel_launch(void* const* d_in, const int* in_sizes, int n_in,
                              void* d_out, int out_size, void* d_ws, size_t ws_size,
                              hipStream_t stream) {
    const float* ue   = (const float*)d_in[0];
    const float* ie   = (const float*)d_in[1];
    const int*   um   = (const int*)d_in[2];
    const int*   im   = (const int*)d_in[3];
    const int*   rows = (const int*)d_in[4];
    const int*   cols = (const int*)d_in[5];
    const int*   users = (const int*)d_in[7];
    const int*   pos   = (const int*)d_in[8];
    const int*   neg   = (const int*)d_in[9];
    int nnz = in_sizes[4];

    float* out = (float*)d_out;

    // workspace layout (16B-aligned bf16 node buffers first)
    unsigned short* Y1 = (unsigned short*)d_ws;         // NNODES*D bf16
    unsigned short* X2 = Y1 + (size_t)NNODES * D;       // NNODES*D bf16
    int*   deg     = (int*)(X2 + (size_t)NNODES * D);   // NNODES
    int*   row_ptr = deg + NNODES;                      // NNODES+1
    int*   sizes   = row_ptr + NNODES + 1;              // NNODES
    int*   sums    = sizes + NNODES;                    // up to 4096
    int*   wcnt    = sums + 4096;                       // [0]=wl1_cnt [1]=wl2_cnt
    int*   cnt1    = wcnt + 16;                         // 2344 (+pad)
    int*   cnt2    = cnt1 + 2360;                       // 2344 (+pad)
    float* dinv    = (float*)(cnt2 + 2360);             // NNODES
    int*   pcol    = (int*)(dinv + NNODES);             // nnz
    char*  flag1   = (char*)(pcol + nnz);               // NNODES
    char*  flag2   = flag1 + NNODES;                    // NNODES
    int*   wl1     = (int*)(((uintptr_t)(flag2 + NNODES) + 15) & ~(uintptr_t)15);
    int*   wl2     = wl1 + NNODES;
    int*   rank    = wl2 + NNODES;                      // nnz

    const int blk = 256;
    const int scan_blocks = (NNODES + 255) / 256;       // 2344
    int chunks = (nnz + 255) / 256;                     // 4688
    int nst = (chunks + 7) / 8;                         // 586 supertiles
    int nhist = chunks * 8;                             // hist blocks (chunk x bucket)
    int seed_blocks = (3 * B + blk - 1) / blk;          // 96
    // sizes coverage: nst*4*8 = 18752 >= 18750 ILP-2 blocks needed

    hipMemsetAsync(deg, 0, (size_t)NNODES * sizeof(int), stream);
    hipMemsetAsync(flag1, 0, (size_t)2 * NNODES, stream);

    // --- K1: histX + rank capture + seed (quiet L2 for atomics) ---
    k_hrs<<<nhist + seed_blocks, blk, 0, stream>>>(rows, deg, rank,
                                                   users, pos, neg,
                                                   flag1, flag2, nnz, nhist);

    // --- scans; scan3 carries pass1 tail ---
    k_scan1<<<scan_blocks, 256, 0, stream>>>(deg, sums, dinv, NNODES);
    k_scan2<<<1, 1024, 0, stream>>>(sums, scan_blocks);
    k_scan3p1<<<scan_blocks + chunks, blk, 0, stream>>>(deg, sums, row_ptr,
                                                        rows, cols, flag2,
                                                        nnz, scan_blocks);

    // --- K2: deterministic scatter (atomic-free) || mask-sizes stream ---
    k_fatS<<<nst * 12 * 8, blk, 0, stream>>>(rows, cols, rank, row_ptr, pcol,
                                             um, im, sizes, nnz);

    // --- mark pass2 (ILP-4 edge blocks) + per-block flag2 counts ---
    {
        int eb = (nnz + 1023) / 1024;                   // 1172
        k_pass2<<<eb + scan_blocks, blk, 0, stream>>>(rows, cols, flag2, flag1,
                                                      cnt2, nnz, eb);
    }

    // --- worklist compaction: count flag1, dual scan, ballot-rank fill ---
    k_cnt1<<<scan_blocks, blk, 0, stream>>>(flag1, cnt1);
    k_scan_dual<<<1, 1024, 0, stream>>>(cnt1, cnt2, scan_blocks, wcnt, wcnt + 1);
    k_fill<<<scan_blocks, blk, 0, stream>>>(flag1, flag2, cnt1, cnt2, wl1, wl2);

    int n_full = NNODES * 8;
    int n_samp = 3 * B * 8;

    // layer 1 over wl1 (dense sorted waves)
    k_spmm1<<<(n_full + blk - 1) / blk, blk, 0, stream>>>(row_ptr, pcol, dinv, sizes,
                                                          wl1, wcnt,
                                                          ue, ie, (unsigned*)Y1);
    // layer 2 over wl2 (dense sorted waves)
    k_spmm2<<<(n_full + blk - 1) / blk, blk, 0, stream>>>(row_ptr, pcol, dinv,
                                                          wl2, wcnt + 1,
                                                          (const unsigned*)Y1, (unsigned*)X2);
    // layer 3: sampled rows, fused epilogue + ego
    k_spmm3<<<(n_samp + blk - 1) / blk, blk, 0, stream>>>(row_ptr, pcol, dinv, sizes,
                                                          ue, ie,
                                                          (const unsigned*)Y1,
                                                          (const unsigned*)X2,
                                                          users, pos, neg, out);
}

// Round 14
// 211.451 us; speedup vs baseline: 1.2400x; 1.0195x over previous
//
#include <hip/hip_runtime.h>

#define N_USERS 400000
#define N_ITEMS 200000
#define NNODES  600000   // N_USERS + N_ITEMS
#define D 64
#define B 8192
#define NBKT 8

typedef int v4i __attribute__((ext_vector_type(4)));

// ---------------------------------------------------------------------------
// bf16 helpers
// ---------------------------------------------------------------------------
__device__ __forceinline__ float bflo(unsigned u) { return __uint_as_float(u << 16); }
__device__ __forceinline__ float bfhi(unsigned u) { return __uint_as_float(u & 0xffff0000u); }
__device__ __forceinline__ unsigned f2bf(float f) {   // round-to-nearest-even
    unsigned u = __float_as_uint(f);
    unsigned r = u + 0x7fffu + ((u >> 16) & 1u);
    return r >> 16;
}

// acc[0..7] += v * bf16x8(word4)
__device__ __forceinline__ void unpack_fma(float* acc, uint4 wv, float v) {
    acc[0] += v * bflo(wv.x); acc[1] += v * bfhi(wv.x);
    acc[2] += v * bflo(wv.y); acc[3] += v * bfhi(wv.y);
    acc[4] += v * bflo(wv.z); acc[5] += v * bfhi(wv.z);
    acc[6] += v * bflo(wv.w); acc[7] += v * bfhi(wv.w);
}

// Bucket map balanced by expected edge count.
__device__ __forceinline__ int bucket_of(int r) {
    return (r < N_USERS) ? (r / 100000) : (4 + (r - N_USERS) / 50000);
}

// ---------------------------------------------------------------------------
// K1: XCD-filtered hist + rank capture (R13, validated: atomic's return value
// becomes the deterministic scatter rank) + sample seed. Quiet L2.
// ---------------------------------------------------------------------------
__global__ void k_hrs(const int* __restrict__ rows, int* __restrict__ deg,
                      int* __restrict__ rank,
                      const int* __restrict__ users, const int* __restrict__ pos,
                      const int* __restrict__ neg,
                      char* __restrict__ flag1, char* __restrict__ flag2,
                      int nnz, int nhist) {
    int bid = blockIdx.x;
    int t = threadIdx.x;
    if (bid < nhist) {
        int x = bid & 7;
        int e = (bid >> 3) * 256 + t;
        if (e >= nnz) return;
        int r = rows[e];
        if (bucket_of(r) == x) rank[e] = atomicAdd(&deg[r], 1);
    } else {
        int slot2 = (bid - nhist) * 256 + t;
        if (slot2 >= 3 * B) return;
        int set = slot2 / B;
        int b = slot2 - set * B;
        int r;
        if (set == 0)      r = users[b];
        else if (set == 1) r = N_USERS + pos[b];
        else               r = N_USERS + neg[b];
        flag2[r] = 1;
        flag1[r] = 1;
    }
}

// ---------------------------------------------------------------------------
// s1p1: scan1 (per-block excl scan of deg + dinv) || COO mark-pass1 (ILP-4).
// pass1 depends only on K1's seed, not the scans -> free overlap.
// pass1 race: monotone 0->1, benign superset.
// ---------------------------------------------------------------------------
__global__ void k_s1p1(int* __restrict__ deg, int* __restrict__ sums,
                       float* __restrict__ dinv,
                       const int* __restrict__ rows, const int* __restrict__ cols,
                       char* __restrict__ flag2, int nnz, int scan_blocks) {
    int bid = blockIdx.x;
    int t = threadIdx.x;
    if (bid < scan_blocks) {
        __shared__ int lds[256];
        int i = bid * 256 + t;
        int v = (i < NNODES) ? deg[i] : 0;
        if (i < NNODES) dinv[i] = (v > 0) ? (float)(1.0 / sqrt((double)v)) : 0.0f;
        lds[t] = v;
        __syncthreads();
        for (int off = 1; off < 256; off <<= 1) {
            int tv = (t >= off) ? lds[t - off] : 0;
            __syncthreads();
            lds[t] += tv;
            __syncthreads();
        }
        int inc = lds[t];
        if (i < NNODES) deg[i] = inc - v;
        if (t == 255) sums[bid] = inc;
    } else {
        int base = (bid - scan_blocks) * 1024 + t;
        int r4[4], c4[4];
        #pragma unroll
        for (int k = 0; k < 4; ++k) {
            int e = base + k * 256;
            r4[k] = (e < nnz) ? rows[e] : -1;
            c4[k] = (e < nnz) ? cols[e] : 0;
        }
        char f4[4];
        #pragma unroll
        for (int k = 0; k < 4; ++k) f4[k] = (r4[k] >= 0) ? flag2[r4[k]] : (char)0;
        #pragma unroll
        for (int k = 0; k < 4; ++k) if (f4[k]) flag2[c4[k]] = 1;
    }
}

__global__ void k_scan2(int* __restrict__ sums, int n) {
    __shared__ int lds[1024];
    __shared__ int carry;
    if (threadIdx.x == 0) carry = 0;
    __syncthreads();
    for (int base = 0; base < n; base += 1024) {
        int i = base + threadIdx.x;
        int v = (i < n) ? sums[i] : 0;
        lds[threadIdx.x] = v;
        __syncthreads();
        for (int off = 1; off < 1024; off <<= 1) {
            int t = (threadIdx.x >= off) ? lds[threadIdx.x - off] : 0;
            __syncthreads();
            lds[threadIdx.x] += t;
            __syncthreads();
        }
        int inc = lds[threadIdx.x];
        if (i < n) sums[i] = (inc - v) + carry;
        __syncthreads();
        if (threadIdx.x == 1023) carry += lds[1023];
        __syncthreads();
    }
}

// ---------------------------------------------------------------------------
// s3p2: scan3 (row_ptr finalize) || mark-pass2 (ILP-4) || flag-tail(+cnt2).
// pass2 depends on flag2 final (after s1p1's pass1), not on row_ptr.
// ---------------------------------------------------------------------------
__global__ void k_s3p2(const int* __restrict__ deg, const int* __restrict__ sums,
                       int* __restrict__ row_ptr,
                       const int* __restrict__ rows, const int* __restrict__ cols,
                       const char* __restrict__ flag2, char* __restrict__ flag1,
                       int* __restrict__ cnt2, int nnz, int scan_blocks, int eb) {
    int bid = blockIdx.x;
    int t = threadIdx.x;
    if (bid < scan_blocks) {
        int i = bid * 256 + t;
        if (i >= NNODES) return;
        row_ptr[i] = deg[i] + sums[i >> 8];
        if (i == 0) row_ptr[NNODES] = nnz;
    } else if (bid < scan_blocks + eb) {
        int base = (bid - scan_blocks) * 1024 + t;
        int r4[4], c4[4];
        #pragma unroll
        for (int k = 0; k < 4; ++k) {
            int e = base + k * 256;
            r4[k] = (e < nnz) ? rows[e] : -1;
            c4[k] = (e < nnz) ? cols[e] : 0;
        }
        char f4[4];
        #pragma unroll
        for (int k = 0; k < 4; ++k) f4[k] = (r4[k] >= 0) ? flag2[r4[k]] : (char)0;
        #pragma unroll
        for (int k = 0; k < 4; ++k) if (f4[k]) flag1[c4[k]] = 1;
    } else {
        int tb = bid - scan_blocks - eb;
        int r = tb * 256 + t;
        char f = (r < NNODES) ? flag2[r] : 0;
        if (f) flag1[r] = 1;
        unsigned long long bal = __ballot(f != 0);
        __shared__ int ws[4];
        int lane = t & 63, wv = t >> 6;
        if (lane == 0) ws[wv] = (int)__popcll(bal);
        __syncthreads();
        if (t == 0) cnt2[tb] = ws[0] + ws[1] + ws[2] + ws[3];
    }
}

// ---------------------------------------------------------------------------
// K2: deterministic scatter (atomic-free, XCD write-window filter) ||
// mask-popcount stream (ILP-2) || cnt1 tail (flag1 final after s3p2).
// bid < nsc: x=bid&7, g=bid>>3, st=g/12, slot=g-st*12.
//   slot0..7: scatter chunk st*8+slot, filter bucket x.
//   slot8..11: sizes ILP-2 blocks.
// bid >= nsc: cnt1 row-tile bid-nsc.
// ---------------------------------------------------------------------------
__global__ void k_fatS(const int* __restrict__ rows, const int* __restrict__ cols,
                       const int* __restrict__ rank, const int* __restrict__ row_ptr,
                       int* __restrict__ pcol,
                       const int* __restrict__ um, const int* __restrict__ im,
                       int* __restrict__ sizes,
                       const char* __restrict__ flag1, int* __restrict__ cnt1,
                       int nnz, int nsc) {
    int bid = blockIdx.x;
    int t = threadIdx.x;
    if (bid >= nsc) {
        int tb = bid - nsc;
        int r = tb * 256 + t;
        char f = (r < NNODES) ? flag1[r] : 0;
        unsigned long long bal = __ballot(f != 0);
        __shared__ int ws[4];
        int lane = t & 63, wv = t >> 6;
        if (lane == 0) ws[wv] = (int)__popcll(bal);
        __syncthreads();
        if (t == 0) cnt1[tb] = ws[0] + ws[1] + ws[2] + ws[3];
        return;
    }
    int x = bid & 7;
    int g = bid >> 3;
    int st = g / 12;
    int slot = g - st * 12;
    if (slot < 8) {
        int e = (st * 8 + slot) * 256 + t;
        if (e >= nnz) return;
        int r = rows[e];
        if (bucket_of(r) != x) return;
        pcol[row_ptr[r] + rank[e]] = cols[e];
    } else {
        int sb = (st * 4 + (slot - 8)) * 8 + x;
        int r = sb * 32 + (t >> 3);
        int q = t & 7;
        if (r >= NNODES) return;
        const v4i* p = (const v4i*)((r < N_USERS) ? um + (size_t)r * D
                                                  : im + (size_t)(r - N_USERS) * D);
        v4i v0 = __builtin_nontemporal_load(p + q);
        v4i v1 = __builtin_nontemporal_load(p + 8 + q);
        int s = v0[0] + v0[1] + v0[2] + v0[3] + v1[0] + v1[1] + v1[2] + v1[3];
        s += __shfl_xor(s, 1);
        s += __shfl_xor(s, 2);
        s += __shfl_xor(s, 4);
        if (q == 0) sizes[r] = s;
    }
}

// single-block exclusive scan of TWO count arrays (in place) + totals
__global__ void k_scan_dual(int* __restrict__ a, int* __restrict__ b, int n,
                            int* __restrict__ totA, int* __restrict__ totB) {
    __shared__ int lds[1024];
    __shared__ int carry;
    for (int pass = 0; pass < 2; ++pass) {
        int* arr = pass ? b : a;
        if (threadIdx.x == 0) carry = 0;
        __syncthreads();
        for (int base = 0; base < n; base += 1024) {
            int i = base + threadIdx.x;
            int v = (i < n) ? arr[i] : 0;
            lds[threadIdx.x] = v;
            __syncthreads();
            for (int off = 1; off < 1024; off <<= 1) {
                int t = (threadIdx.x >= off) ? lds[threadIdx.x - off] : 0;
                __syncthreads();
                lds[threadIdx.x] += t;
                __syncthreads();
            }
            int inc = lds[threadIdx.x];
            if (i < n) arr[i] = (inc - v) + carry;
            __syncthreads();
            if (threadIdx.x == 1023) carry += lds[1023];
            __syncthreads();
        }
        if (threadIdx.x == 0) { if (pass) *totB = carry; else *totA = carry; }
        __syncthreads();
    }
}

// ballot-rank fill of both worklists (sorted order -> pcol/y1 locality)
__global__ void k_fill(const char* __restrict__ flag1, const char* __restrict__ flag2,
                       const int* __restrict__ cnt1, const int* __restrict__ cnt2,
                       int* __restrict__ wl1, int* __restrict__ wl2) {
    int tb = blockIdx.x;
    int t = threadIdx.x;
    int r = tb * 256 + t;
    bool a = (r < NNODES) && flag1[r];
    bool b = (r < NNODES) && flag2[r];
    int lane = t & 63, wv = t >> 6;
    unsigned long long lt = (1ull << lane) - 1ull;
    unsigned long long ba = __ballot(a);
    unsigned long long bb = __ballot(b);
    __shared__ int wa[4], wb[4];
    if (lane == 0) { wa[wv] = (int)__popcll(ba); wb[wv] = (int)__popcll(bb); }
    __syncthreads();
    int offA = 0, offB = 0;
    for (int i = 0; i < wv; ++i) { offA += wa[i]; offB += wb[i]; }
    if (a) wl1[cnt1[tb] + offA + (int)__popcll(ba & lt)] = r;
    if (b) wl2[cnt2[tb] + offB + (int)__popcll(bb & lt)] = r;
}

// ---------------------------------------------------------------------------
// Layer-1 SPMM over the wl1 worklist (dense waves). 8 threads/row, unroll x2.
// ---------------------------------------------------------------------------
__global__ void k_spmm1(const int* __restrict__ row_ptr, const int* __restrict__ pcol,
                        const float* __restrict__ dinv, const int* __restrict__ sizes,
                        const int* __restrict__ wl1, const int* __restrict__ wl1_cnt,
                        const float* __restrict__ ue, const float* __restrict__ ie,
                        unsigned* __restrict__ y1) {
    int tid = blockIdx.x * blockDim.x + threadIdx.x;
    int w = tid >> 3;
    if (w >= *wl1_cnt) return;
    int r = wl1[w];
    int c8 = (tid & 7) << 3;          // f32 col base
    int s = row_ptr[r];
    int e = row_ptr[r + 1];
    float dr = dinv[r];
    float acc[8] = {0.f, 0.f, 0.f, 0.f, 0.f, 0.f, 0.f, 0.f};
    int i = s;
    for (; i + 1 < e; i += 2) {
        int c0 = pcol[i], c1 = pcol[i + 1];
        float v0 = dr * dinv[c0], v1 = dr * dinv[c1];
        int sz0 = sizes[c0], sz1 = sizes[c1];
        const float* p0 = ((c0 < N_USERS) ? ue + (size_t)c0 * D
                                          : ie + (size_t)(c0 - N_USERS) * D) + c8;
        const float* p1 = ((c1 < N_USERS) ? ue + (size_t)c1 * D
                                          : ie + (size_t)(c1 - N_USERS) * D) + c8;
        float4 a0 = *(const float4*)p0;
        float4 a1 = *(const float4*)(p0 + 4);
        float4 b0 = *(const float4*)p1;
        float4 b1 = *(const float4*)(p1 + 4);
        acc[0] += v0 * ((c8 + 0 < sz0) ? a0.x : 0.f) + v1 * ((c8 + 0 < sz1) ? b0.x : 0.f);
        acc[1] += v0 * ((c8 + 1 < sz0) ? a0.y : 0.f) + v1 * ((c8 + 1 < sz1) ? b0.y : 0.f);
        acc[2] += v0 * ((c8 + 2 < sz0) ? a0.z : 0.f) + v1 * ((c8 + 2 < sz1) ? b0.z : 0.f);
        acc[3] += v0 * ((c8 + 3 < sz0) ? a0.w : 0.f) + v1 * ((c8 + 3 < sz1) ? b0.w : 0.f);
        acc[4] += v0 * ((c8 + 4 < sz0) ? a1.x : 0.f) + v1 * ((c8 + 4 < sz1) ? b1.x : 0.f);
        acc[5] += v0 * ((c8 + 5 < sz0) ? a1.y : 0.f) + v1 * ((c8 + 5 < sz1) ? b1.y : 0.f);
        acc[6] += v0 * ((c8 + 6 < sz0) ? a1.z : 0.f) + v1 * ((c8 + 6 < sz1) ? b1.z : 0.f);
        acc[7] += v0 * ((c8 + 7 < sz0) ? a1.w : 0.f) + v1 * ((c8 + 7 < sz1) ? b1.w : 0.f);
    }
    if (i < e) {
        int c = pcol[i];
        float v = dr * dinv[c];
        int sz = sizes[c];
        const float* p = ((c < N_USERS) ? ue + (size_t)c * D
                                        : ie + (size_t)(c - N_USERS) * D) + c8;
        float4 e0 = *(const float4*)p;
        float4 e1 = *(const float4*)(p + 4);
        acc[0] += v * ((c8 + 0 < sz) ? e0.x : 0.f);
        acc[1] += v * ((c8 + 1 < sz) ? e0.y : 0.f);
        acc[2] += v * ((c8 + 2 < sz) ? e0.z : 0.f);
        acc[3] += v * ((c8 + 3 < sz) ? e0.w : 0.f);
        acc[4] += v * ((c8 + 4 < sz) ? e1.x : 0.f);
        acc[5] += v * ((c8 + 5 < sz) ? e1.y : 0.f);
        acc[6] += v * ((c8 + 6 < sz) ? e1.z : 0.f);
        acc[7] += v * ((c8 + 7 < sz) ? e1.w : 0.f);
    }
    uint4 o;
    o.x = f2bf(acc[0]) | (f2bf(acc[1]) << 16);
    o.y = f2bf(acc[2]) | (f2bf(acc[3]) << 16);
    o.z = f2bf(acc[4]) | (f2bf(acc[5]) << 16);
    o.w = f2bf(acc[6]) | (f2bf(acc[7]) << 16);
    *(uint4*)(y1 + (size_t)r * 32 + (tid & 7) * 4) = o;
}

// ---------------------------------------------------------------------------
// Layer-2 bf16 SPMM over the wl2 worklist: x2[r] = sum val * y1[col].
// ---------------------------------------------------------------------------
__global__ void k_spmm2(const int* __restrict__ row_ptr, const int* __restrict__ pcol,
                        const float* __restrict__ dinv,
                        const int* __restrict__ wl2, const int* __restrict__ wl2_cnt,
                        const unsigned* __restrict__ y1, unsigned* __restrict__ x2) {
    int tid = blockIdx.x * blockDim.x + threadIdx.x;
    int w = tid >> 3;
    if (w >= *wl2_cnt) return;
    int r = wl2[w];
    int cp = (tid & 7) << 2;
    int s = row_ptr[r];
    int e = row_ptr[r + 1];
    float dr = dinv[r];
    float acc[8] = {0.f, 0.f, 0.f, 0.f, 0.f, 0.f, 0.f, 0.f};
    int i = s;
    for (; i + 1 < e; i += 2) {
        int c0 = pcol[i], c1 = pcol[i + 1];
        float v0 = dr * dinv[c0], v1 = dr * dinv[c1];
        uint4 w0 = *(const uint4*)(y1 + (size_t)c0 * 32 + cp);
        uint4 w1 = *(const uint4*)(y1 + (size_t)c1 * 32 + cp);
        unpack_fma(acc, w0, v0);
        unpack_fma(acc, w1, v1);
    }
    if (i < e) {
        int c0 = pcol[i];
        float v0 = dr * dinv[c0];
        uint4 w0 = *(const uint4*)(y1 + (size_t)c0 * 32 + cp);
        unpack_fma(acc, w0, v0);
    }
    uint4 o;
    o.x = f2bf(acc[0]) | (f2bf(acc[1]) << 16);
    o.y = f2bf(acc[2]) | (f2bf(acc[3]) << 16);
    o.z = f2bf(acc[4]) | (f2bf(acc[5]) << 16);
    o.w = f2bf(acc[6]) | (f2bf(acc[7]) << 16);
    *(uint4*)(x2 + (size_t)r * 32 + cp) = o;
}

// ---------------------------------------------------------------------------
// Final sampled layer, fused epilogue + ego.
// ---------------------------------------------------------------------------
__global__ void k_spmm3(const int* __restrict__ row_ptr, const int* __restrict__ pcol,
                        const float* __restrict__ dinv, const int* __restrict__ sizes,
                        const float* __restrict__ ue, const float* __restrict__ ie,
                        const unsigned* __restrict__ y1, const unsigned* __restrict__ x2,
                        const int* __restrict__ users, const int* __restrict__ pos,
                        const int* __restrict__ neg, float* __restrict__ out) {
    int tid = blockIdx.x * blockDim.x + threadIdx.x;
    int slot = tid >> 3;
    if (slot >= 3 * B) return;
    int cp = (tid & 7) << 2;          // uint base
    int c8 = (tid & 7) << 3;          // f32 col base
    int set = slot / B;
    int b = slot - set * B;
    int r;
    if (set == 0)      r = users[b];
    else if (set == 1) r = N_USERS + pos[b];
    else               r = N_USERS + neg[b];
    int s = row_ptr[r];
    int e = row_ptr[r + 1];
    float dr = dinv[r];
    float acc[8] = {0.f, 0.f, 0.f, 0.f, 0.f, 0.f, 0.f, 0.f};
    uint4 g1 = *(const uint4*)(y1 + (size_t)r * 32 + cp);
    uint4 g2 = *(const uint4*)(x2 + (size_t)r * 32 + cp);
    unpack_fma(acc, g1, 1.0f);
    unpack_fma(acc, g2, 1.0f);
    int i = s;
    for (; i + 1 < e; i += 2) {
        int c0 = pcol[i], c1 = pcol[i + 1];
        float v0 = dr * dinv[c0], v1 = dr * dinv[c1];
        uint4 w0 = *(const uint4*)(x2 + (size_t)c0 * 32 + cp);
        uint4 w1 = *(const uint4*)(x2 + (size_t)c1 * 32 + cp);
        unpack_fma(acc, w0, v0);
        unpack_fma(acc, w1, v1);
    }
    if (i < e) {
        int c0 = pcol[i];
        float v0 = dr * dinv[c0];
        uint4 w0 = *(const uint4*)(x2 + (size_t)c0 * 32 + cp);
        unpack_fma(acc, w0, v0);
    }
    const float* p = ((r < N_USERS) ? ue + (size_t)r * D
                                    : ie + (size_t)(r - N_USERS) * D) + c8;
    float4 e0 = *(const float4*)p;
    float4 e1 = *(const float4*)(p + 4);
    int sz = sizes[r];
    e0.x = (c8 + 0 < sz) ? e0.x : 0.f; e0.y = (c8 + 1 < sz) ? e0.y : 0.f;
    e0.z = (c8 + 2 < sz) ? e0.z : 0.f; e0.w = (c8 + 3 < sz) ? e0.w : 0.f;
    e1.x = (c8 + 4 < sz) ? e1.x : 0.f; e1.y = (c8 + 5 < sz) ? e1.y : 0.f;
    e1.z = (c8 + 6 < sz) ? e1.z : 0.f; e1.w = (c8 + 7 < sz) ? e1.w : 0.f;
    float4 oa, ob;
    oa.x = (e0.x + acc[0]) * 0.25f; oa.y = (e0.y + acc[1]) * 0.25f;
    oa.z = (e0.z + acc[2]) * 0.25f; oa.w = (e0.w + acc[3]) * 0.25f;
    ob.x = (e1.x + acc[4]) * 0.25f; ob.y = (e1.y + acc[5]) * 0.25f;
    ob.z = (e1.z + acc[6]) * 0.25f; ob.w = (e1.w + acc[7]) * 0.25f;
    float* o0 = out + (size_t)slot * D + c8;
    float* o1 = out + (size_t)(3 * B + slot) * D + c8;
    *(float4*)o0 = oa; *(float4*)(o0 + 4) = ob;
    *(float4*)o1 = e0; *(float4*)(o1 + 4) = e1;
}

extern "C" void kernel_launch(void* const* d_in, const int* in_sizes, int n_in,
                              void* d_out, int out_size, void* d_ws, size_t ws_size,
                              hipStream_t stream) {
    const float* ue   = (const float*)d_in[0];
    const float* ie   = (const float*)d_in[1];
    const int*   um   = (const int*)d_in[2];
    const int*   im   = (const int*)d_in[3];
    const int*   rows = (const int*)d_in[4];
    const int*   cols = (const int*)d_in[5];
    const int*   users = (const int*)d_in[7];
    const int*   pos   = (const int*)d_in[8];
    const int*   neg   = (const int*)d_in[9];
    int nnz = in_sizes[4];

    float* out = (float*)d_out;

    // workspace layout (16B-aligned bf16 node buffers first)
    unsigned short* Y1 = (unsigned short*)d_ws;         // NNODES*D bf16
    unsigned short* X2 = Y1 + (size_t)NNODES * D;       // NNODES*D bf16
    int*   deg     = (int*)(X2 + (size_t)NNODES * D);   // NNODES
    int*   row_ptr = deg + NNODES;                      // NNODES+1
    int*   sizes   = row_ptr + NNODES + 1;              // NNODES
    int*   sums    = sizes + NNODES;                    // up to 4096
    int*   wcnt    = sums + 4096;                       // [0]=wl1_cnt [1]=wl2_cnt
    int*   cnt1    = wcnt + 16;                         // 2344 (+pad)
    int*   cnt2    = cnt1 + 2360;                       // 2344 (+pad)
    float* dinv    = (float*)(cnt2 + 2360);             // NNODES
    int*   pcol    = (int*)(dinv + NNODES);             // nnz
    char*  flag1   = (char*)(pcol + nnz);               // NNODES
    char*  flag2   = flag1 + NNODES;                    // NNODES
    int*   wl1     = (int*)(((uintptr_t)(flag2 + NNODES) + 15) & ~(uintptr_t)15);
    int*   wl2     = wl1 + NNODES;
    int*   rank    = wl2 + NNODES;                      // nnz

    const int blk = 256;
    const int scan_blocks = (NNODES + 255) / 256;       // 2344
    int chunks = (nnz + 255) / 256;                     // 4688
    int nst = (chunks + 7) / 8;                         // 586 supertiles
    int nhist = chunks * 8;                             // hist blocks (chunk x bucket)
    int seed_blocks = (3 * B + blk - 1) / blk;          // 96
    int eb = (nnz + 1023) / 1024;                       // ILP-4 edge blocks (1172)
    int nsc = nst * 12 * 8;                             // fatS main grid
    // sizes coverage: nst*4*8 = 18752 >= 18750 ILP-2 blocks needed

    hipMemsetAsync(deg, 0, (size_t)NNODES * sizeof(int), stream);
    hipMemsetAsync(flag1, 0, (size_t)2 * NNODES, stream);

    // --- K1: histX + rank capture + seed (quiet L2 for atomics) ---
    k_hrs<<<nhist + seed_blocks, blk, 0, stream>>>(rows, deg, rank,
                                                   users, pos, neg,
                                                   flag1, flag2, nnz, nhist);

    // --- scan1 || pass1(ILP-4) ---
    k_s1p1<<<scan_blocks + eb, blk, 0, stream>>>(deg, sums, dinv,
                                                 rows, cols, flag2, nnz, scan_blocks);

    // --- scan2 ---
    k_scan2<<<1, 1024, 0, stream>>>(sums, scan_blocks);

    // --- scan3 || pass2(ILP-4) || flag-tail(+cnt2) ---
    k_s3p2<<<scan_blocks + eb + scan_blocks, blk, 0, stream>>>(
        deg, sums, row_ptr, rows, cols, flag2, flag1, cnt2, nnz, scan_blocks, eb);

    // --- K2: deterministic scatter || mask-sizes stream || cnt1 tail ---
    k_fatS<<<nsc + scan_blocks, blk, 0, stream>>>(rows, cols, rank, row_ptr, pcol,
                                                  um, im, sizes, flag1, cnt1,
                                                  nnz, nsc);

    // --- worklist compaction: dual scan + ballot-rank fill ---
    k_scan_dual<<<1, 1024, 0, stream>>>(cnt1, cnt2, scan_blocks, wcnt, wcnt + 1);
    k_fill<<<scan_blocks, blk, 0, stream>>>(flag1, flag2, cnt1, cnt2, wl1, wl2);

    int n_full = NNODES * 8;
    int n_samp = 3 * B * 8;

    // layer 1 over wl1 (dense sorted waves)
    k_spmm1<<<(n_full + blk - 1) / blk, blk, 0, stream>>>(row_ptr, pcol, dinv, sizes,
                                                          wl1, wcnt,
                                                          ue, ie, (unsigned*)Y1);
    // layer 2 over wl2 (dense sorted waves)
    k_spmm2<<<(n_full + blk - 1) / blk, blk, 0, stream>>>(row_ptr, pcol, dinv,
                                                          wl2, wcnt + 1,
                                                          (const unsigned*)Y1, (unsigned*)X2);
    // layer 3: sampled rows, fused epilogue + ego
    k_spmm3<<<(n_samp + blk - 1) / blk, blk, 0, stream>>>(row_ptr, pcol, dinv, sizes,
                                                          ue, ie,
                                                          (const unsigned*)Y1,
                                                          (const unsigned*)X2,
                                                          users, pos, neg, out);
}

// Round 15
// 210.190 us; speedup vs baseline: 1.2474x; 1.0060x over previous
//
#include <hip/hip_runtime.h>

#define N_USERS 400000
#define N_ITEMS 200000
#define NNODES  600000   // N_USERS + N_ITEMS
#define D 64
#define B 8192
#define NBKT 8

typedef int v4i __attribute__((ext_vector_type(4)));

// ---------------------------------------------------------------------------
// bf16 helpers
// ---------------------------------------------------------------------------
__device__ __forceinline__ float bflo(unsigned u) { return __uint_as_float(u << 16); }
__device__ __forceinline__ float bfhi(unsigned u) { return __uint_as_float(u & 0xffff0000u); }
__device__ __forceinline__ unsigned f2bf(float f) {   // round-to-nearest-even
    unsigned u = __float_as_uint(f);
    unsigned r = u + 0x7fffu + ((u >> 16) & 1u);
    return r >> 16;
}

// acc[0..7] += v * bf16x8(word4)
__device__ __forceinline__ void unpack_fma(float* acc, uint4 wv, float v) {
    acc[0] += v * bflo(wv.x); acc[1] += v * bfhi(wv.x);
    acc[2] += v * bflo(wv.y); acc[3] += v * bfhi(wv.y);
    acc[4] += v * bflo(wv.z); acc[5] += v * bfhi(wv.z);
    acc[6] += v * bflo(wv.w); acc[7] += v * bfhi(wv.w);
}

// Bucket map balanced by expected edge count.
__device__ __forceinline__ int bucket_of(int r) {
    return (r < N_USERS) ? (r / 100000) : (4 + (r - N_USERS) / 50000);
}

// ---------------------------------------------------------------------------
// K1: XCD-filtered hist + rank capture (validated R13) + sample seed.
// ---------------------------------------------------------------------------
__global__ void k_hrs(const int* __restrict__ rows, int* __restrict__ deg,
                      int* __restrict__ rank,
                      const int* __restrict__ users, const int* __restrict__ pos,
                      const int* __restrict__ neg,
                      char* __restrict__ flag1, char* __restrict__ flag2,
                      int nnz, int nhist) {
    int bid = blockIdx.x;
    int t = threadIdx.x;
    if (bid < nhist) {
        int x = bid & 7;
        int e = (bid >> 3) * 256 + t;
        if (e >= nnz) return;
        int r = rows[e];
        if (bucket_of(r) == x) rank[e] = atomicAdd(&deg[r], 1);
    } else {
        int slot2 = (bid - nhist) * 256 + t;
        if (slot2 >= 3 * B) return;
        int set = slot2 / B;
        int b = slot2 - set * B;
        int r;
        if (set == 0)      r = users[b];
        else if (set == 1) r = N_USERS + pos[b];
        else               r = N_USERS + neg[b];
        flag2[r] = 1;
        flag1[r] = 1;
    }
}

// ---------------------------------------------------------------------------
// s1p1: scan1 (per-block excl scan of deg; dinv -> dv[2r].x) || pass1 (ILP-4).
// pass1 race: monotone 0->1, benign superset.
// ---------------------------------------------------------------------------
__global__ void k_s1p1(int* __restrict__ deg, int* __restrict__ sums,
                       int* __restrict__ dv,
                       const int* __restrict__ rows, const int* __restrict__ cols,
                       char* __restrict__ flag2, int nnz, int scan_blocks) {
    int bid = blockIdx.x;
    int t = threadIdx.x;
    if (bid < scan_blocks) {
        __shared__ int lds[256];
        int i = bid * 256 + t;
        int v = (i < NNODES) ? deg[i] : 0;
        if (i < NNODES) {
            float dvf = (v > 0) ? (float)(1.0 / sqrt((double)v)) : 0.0f;
            dv[2 * i] = __float_as_int(dvf);
        }
        lds[t] = v;
        __syncthreads();
        for (int off = 1; off < 256; off <<= 1) {
            int tv = (t >= off) ? lds[t - off] : 0;
            __syncthreads();
            lds[t] += tv;
            __syncthreads();
        }
        int inc = lds[t];
        if (i < NNODES) deg[i] = inc - v;
        if (t == 255) sums[bid] = inc;
    } else {
        int base = (bid - scan_blocks) * 1024 + t;
        int r4[4], c4[4];
        #pragma unroll
        for (int k = 0; k < 4; ++k) {
            int e = base + k * 256;
            r4[k] = (e < nnz) ? rows[e] : -1;
            c4[k] = (e < nnz) ? cols[e] : 0;
        }
        char f4[4];
        #pragma unroll
        for (int k = 0; k < 4; ++k) f4[k] = (r4[k] >= 0) ? flag2[r4[k]] : (char)0;
        #pragma unroll
        for (int k = 0; k < 4; ++k) if (f4[k]) flag2[c4[k]] = 1;
    }
}

__global__ void k_scan2(int* __restrict__ sums, int n) {
    __shared__ int lds[1024];
    __shared__ int carry;
    if (threadIdx.x == 0) carry = 0;
    __syncthreads();
    for (int base = 0; base < n; base += 1024) {
        int i = base + threadIdx.x;
        int v = (i < n) ? sums[i] : 0;
        lds[threadIdx.x] = v;
        __syncthreads();
        for (int off = 1; off < 1024; off <<= 1) {
            int t = (threadIdx.x >= off) ? lds[threadIdx.x - off] : 0;
            __syncthreads();
            lds[threadIdx.x] += t;
            __syncthreads();
        }
        int inc = lds[threadIdx.x];
        if (i < n) sums[i] = (inc - v) + carry;
        __syncthreads();
        if (threadIdx.x == 1023) carry += lds[1023];
        __syncthreads();
    }
}

// ---------------------------------------------------------------------------
// s3p2: scan3 (row_ptr) || mark-pass2 (ILP-4) || flag-tail(+cnt2).
// ---------------------------------------------------------------------------
__global__ void k_s3p2(const int* __restrict__ deg, const int* __restrict__ sums,
                       int* __restrict__ row_ptr,
                       const int* __restrict__ rows, const int* __restrict__ cols,
                       const char* __restrict__ flag2, char* __restrict__ flag1,
                       int* __restrict__ cnt2, int nnz, int scan_blocks, int eb) {
    int bid = blockIdx.x;
    int t = threadIdx.x;
    if (bid < scan_blocks) {
        int i = bid * 256 + t;
        if (i >= NNODES) return;
        row_ptr[i] = deg[i] + sums[i >> 8];
        if (i == 0) row_ptr[NNODES] = nnz;
    } else if (bid < scan_blocks + eb) {
        int base = (bid - scan_blocks) * 1024 + t;
        int r4[4], c4[4];
        #pragma unroll
        for (int k = 0; k < 4; ++k) {
            int e = base + k * 256;
            r4[k] = (e < nnz) ? rows[e] : -1;
            c4[k] = (e < nnz) ? cols[e] : 0;
        }
        char f4[4];
        #pragma unroll
        for (int k = 0; k < 4; ++k) f4[k] = (r4[k] >= 0) ? flag2[r4[k]] : (char)0;
        #pragma unroll
        for (int k = 0; k < 4; ++k) if (f4[k]) flag1[c4[k]] = 1;
    } else {
        int tb = bid - scan_blocks - eb;
        int r = tb * 256 + t;
        char f = (r < NNODES) ? flag2[r] : 0;
        if (f) flag1[r] = 1;
        unsigned long long bal = __ballot(f != 0);
        __shared__ int ws[4];
        int lane = t & 63, wv = t >> 6;
        if (lane == 0) ws[wv] = (int)__popcll(bal);
        __syncthreads();
        if (t == 0) cnt2[tb] = ws[0] + ws[1] + ws[2] + ws[3];
    }
}

// per-block flag1 counts (flag1 final after s3p2)
__global__ void k_cnt1(const char* __restrict__ flag1, int* __restrict__ cnt1) {
    int tb = blockIdx.x;
    int t = threadIdx.x;
    int r = tb * 256 + t;
    char f = (r < NNODES) ? flag1[r] : 0;
    unsigned long long bal = __ballot(f != 0);
    __shared__ int ws[4];
    int lane = t & 63, wv = t >> 6;
    if (lane == 0) ws[wv] = (int)__popcll(bal);
    __syncthreads();
    if (t == 0) cnt1[tb] = ws[0] + ws[1] + ws[2] + ws[3];
}

// single-block exclusive scan of TWO count arrays (in place) + totals
__global__ void k_scan_dual(int* __restrict__ a, int* __restrict__ b, int n,
                            int* __restrict__ totA, int* __restrict__ totB) {
    __shared__ int lds[1024];
    __shared__ int carry;
    for (int pass = 0; pass < 2; ++pass) {
        int* arr = pass ? b : a;
        if (threadIdx.x == 0) carry = 0;
        __syncthreads();
        for (int base = 0; base < n; base += 1024) {
            int i = base + threadIdx.x;
            int v = (i < n) ? arr[i] : 0;
            lds[threadIdx.x] = v;
            __syncthreads();
            for (int off = 1; off < 1024; off <<= 1) {
                int t = (threadIdx.x >= off) ? lds[threadIdx.x - off] : 0;
                __syncthreads();
                lds[threadIdx.x] += t;
                __syncthreads();
            }
            int inc = lds[threadIdx.x];
            if (i < n) arr[i] = (inc - v) + carry;
            __syncthreads();
            if (threadIdx.x == 1023) carry += lds[1023];
            __syncthreads();
        }
        if (threadIdx.x == 0) { if (pass) *totB = carry; else *totA = carry; }
        __syncthreads();
    }
}

// ---------------------------------------------------------------------------
// K2: deterministic scatter (atomic-free, XCD write-window filter) ||
// mask-popcount stream with CONDITIONAL second half (prefix-mask property:
// mask[31]==0 -> second 128B is all zero; P(read) ~0.52 -> stream 153.6->116MB)
// || ballot-rank fill tail (wl1/wl2; hidden under the stream).
// Sizes written to dv[2r+1] ({dinv,size} packed: one cache line per col
// lookup in spmm1 instead of two).
// ---------------------------------------------------------------------------
__global__ void k_fatS(const int* __restrict__ rows, const int* __restrict__ cols,
                       const int* __restrict__ rank, const int* __restrict__ row_ptr,
                       int* __restrict__ pcol,
                       const int* __restrict__ um, const int* __restrict__ im,
                       int* __restrict__ dv,
                       const char* __restrict__ flag1, const char* __restrict__ flag2,
                       const int* __restrict__ cnt1, const int* __restrict__ cnt2,
                       int* __restrict__ wl1, int* __restrict__ wl2,
                       int nnz, int nsc) {
    int bid = blockIdx.x;
    int t = threadIdx.x;
    if (bid >= nsc) {
        // fill tail
        int tb = bid - nsc;
        int r = tb * 256 + t;
        bool a = (r < NNODES) && flag1[r];
        bool b = (r < NNODES) && flag2[r];
        int lane = t & 63, wv = t >> 6;
        unsigned long long lt = (1ull << lane) - 1ull;
        unsigned long long ba = __ballot(a);
        unsigned long long bb = __ballot(b);
        __shared__ int wa[4], wb[4];
        if (lane == 0) { wa[wv] = (int)__popcll(ba); wb[wv] = (int)__popcll(bb); }
        __syncthreads();
        int offA = 0, offB = 0;
        for (int i = 0; i < wv; ++i) { offA += wa[i]; offB += wb[i]; }
        if (a) wl1[cnt1[tb] + offA + (int)__popcll(ba & lt)] = r;
        if (b) wl2[cnt2[tb] + offB + (int)__popcll(bb & lt)] = r;
        return;
    }
    int x = bid & 7;
    int g = bid >> 3;
    int st = g / 12;
    int slot = g - st * 12;
    if (slot < 8) {
        int e = (st * 8 + slot) * 256 + t;
        if (e >= nnz) return;
        int r = rows[e];
        if (bucket_of(r) != x) return;
        pcol[row_ptr[r] + rank[e]] = cols[e];
    } else {
        int sb = (st * 4 + (slot - 8)) * 8 + x;
        int r = sb * 32 + (t >> 3);
        int q = t & 7;
        if (r >= NNODES) return;
        const v4i* p = (const v4i*)((r < N_USERS) ? um + (size_t)r * D
                                                  : im + (size_t)(r - N_USERS) * D);
        v4i v0 = __builtin_nontemporal_load(p + q);        // first 128B of row
        int s = v0[0] + v0[1] + v0[2] + v0[3];
        // prefix-mask: need second half iff mask[31]==1 (lane q==7 holds it)
        int lane = t & 63;
        int m31 = __shfl(v0[3], (lane & 56) | 7, 64);
        if (m31) {
            v4i v1 = __builtin_nontemporal_load(p + 8 + q);
            s += v1[0] + v1[1] + v1[2] + v1[3];
        }
        s += __shfl_xor(s, 1);
        s += __shfl_xor(s, 2);
        s += __shfl_xor(s, 4);
        if (q == 0) dv[2 * r + 1] = s;
    }
}

// ---------------------------------------------------------------------------
// Layer-1 SPMM over wl1 (dense waves). 8 threads/row, unroll x2.
// Per-col side lookup is ONE int2 ({dinv,size}) -> one cache line.
// ---------------------------------------------------------------------------
__global__ void k_spmm1(const int* __restrict__ row_ptr, const int* __restrict__ pcol,
                        const int* __restrict__ dv,
                        const int* __restrict__ wl1, const int* __restrict__ wl1_cnt,
                        const float* __restrict__ ue, const float* __restrict__ ie,
                        unsigned* __restrict__ y1) {
    int tid = blockIdx.x * blockDim.x + threadIdx.x;
    int w = tid >> 3;
    if (w >= *wl1_cnt) return;
    int r = wl1[w];
    int c8 = (tid & 7) << 3;          // f32 col base
    int s = row_ptr[r];
    int e = row_ptr[r + 1];
    float dr = __int_as_float(dv[2 * r]);
    float acc[8] = {0.f, 0.f, 0.f, 0.f, 0.f, 0.f, 0.f, 0.f};
    int i = s;
    for (; i + 1 < e; i += 2) {
        int c0 = pcol[i], c1 = pcol[i + 1];
        int2 d0 = *(const int2*)(dv + 2 * c0);
        int2 d1 = *(const int2*)(dv + 2 * c1);
        float v0 = dr * __int_as_float(d0.x), v1 = dr * __int_as_float(d1.x);
        int sz0 = d0.y, sz1 = d1.y;
        const float* p0 = ((c0 < N_USERS) ? ue + (size_t)c0 * D
                                          : ie + (size_t)(c0 - N_USERS) * D) + c8;
        const float* p1 = ((c1 < N_USERS) ? ue + (size_t)c1 * D
                                          : ie + (size_t)(c1 - N_USERS) * D) + c8;
        float4 a0 = *(const float4*)p0;
        float4 a1 = *(const float4*)(p0 + 4);
        float4 b0 = *(const float4*)p1;
        float4 b1 = *(const float4*)(p1 + 4);
        acc[0] += v0 * ((c8 + 0 < sz0) ? a0.x : 0.f) + v1 * ((c8 + 0 < sz1) ? b0.x : 0.f);
        acc[1] += v0 * ((c8 + 1 < sz0) ? a0.y : 0.f) + v1 * ((c8 + 1 < sz1) ? b0.y : 0.f);
        acc[2] += v0 * ((c8 + 2 < sz0) ? a0.z : 0.f) + v1 * ((c8 + 2 < sz1) ? b0.z : 0.f);
        acc[3] += v0 * ((c8 + 3 < sz0) ? a0.w : 0.f) + v1 * ((c8 + 3 < sz1) ? b0.w : 0.f);
        acc[4] += v0 * ((c8 + 4 < sz0) ? a1.x : 0.f) + v1 * ((c8 + 4 < sz1) ? b1.x : 0.f);
        acc[5] += v0 * ((c8 + 5 < sz0) ? a1.y : 0.f) + v1 * ((c8 + 5 < sz1) ? b1.y : 0.f);
        acc[6] += v0 * ((c8 + 6 < sz0) ? a1.z : 0.f) + v1 * ((c8 + 6 < sz1) ? b1.z : 0.f);
        acc[7] += v0 * ((c8 + 7 < sz0) ? a1.w : 0.f) + v1 * ((c8 + 7 < sz1) ? b1.w : 0.f);
    }
    if (i < e) {
        int c = pcol[i];
        int2 d0 = *(const int2*)(dv + 2 * c);
        float v = dr * __int_as_float(d0.x);
        int sz = d0.y;
        const float* p = ((c < N_USERS) ? ue + (size_t)c * D
                                        : ie + (size_t)(c - N_USERS) * D) + c8;
        float4 e0 = *(const float4*)p;
        float4 e1 = *(const float4*)(p + 4);
        acc[0] += v * ((c8 + 0 < sz) ? e0.x : 0.f);
        acc[1] += v * ((c8 + 1 < sz) ? e0.y : 0.f);
        acc[2] += v * ((c8 + 2 < sz) ? e0.z : 0.f);
        acc[3] += v * ((c8 + 3 < sz) ? e0.w : 0.f);
        acc[4] += v * ((c8 + 4 < sz) ? e1.x : 0.f);
        acc[5] += v * ((c8 + 5 < sz) ? e1.y : 0.f);
        acc[6] += v * ((c8 + 6 < sz) ? e1.z : 0.f);
        acc[7] += v * ((c8 + 7 < sz) ? e1.w : 0.f);
    }
    uint4 o;
    o.x = f2bf(acc[0]) | (f2bf(acc[1]) << 16);
    o.y = f2bf(acc[2]) | (f2bf(acc[3]) << 16);
    o.z = f2bf(acc[4]) | (f2bf(acc[5]) << 16);
    o.w = f2bf(acc[6]) | (f2bf(acc[7]) << 16);
    *(uint4*)(y1 + (size_t)r * 32 + (tid & 7) * 4) = o;
}

// ---------------------------------------------------------------------------
// Layer-2 bf16 SPMM over wl2: x2[r] = sum val * y1[col].
// ---------------------------------------------------------------------------
__global__ void k_spmm2(const int* __restrict__ row_ptr, const int* __restrict__ pcol,
                        const int* __restrict__ dv,
                        const int* __restrict__ wl2, const int* __restrict__ wl2_cnt,
                        const unsigned* __restrict__ y1, unsigned* __restrict__ x2) {
    int tid = blockIdx.x * blockDim.x + threadIdx.x;
    int w = tid >> 3;
    if (w >= *wl2_cnt) return;
    int r = wl2[w];
    int cp = (tid & 7) << 2;
    int s = row_ptr[r];
    int e = row_ptr[r + 1];
    float dr = __int_as_float(dv[2 * r]);
    float acc[8] = {0.f, 0.f, 0.f, 0.f, 0.f, 0.f, 0.f, 0.f};
    int i = s;
    for (; i + 1 < e; i += 2) {
        int c0 = pcol[i], c1 = pcol[i + 1];
        float v0 = dr * __int_as_float(dv[2 * c0]);
        float v1 = dr * __int_as_float(dv[2 * c1]);
        uint4 w0 = *(const uint4*)(y1 + (size_t)c0 * 32 + cp);
        uint4 w1 = *(const uint4*)(y1 + (size_t)c1 * 32 + cp);
        unpack_fma(acc, w0, v0);
        unpack_fma(acc, w1, v1);
    }
    if (i < e) {
        int c0 = pcol[i];
        float v0 = dr * __int_as_float(dv[2 * c0]);
        uint4 w0 = *(const uint4*)(y1 + (size_t)c0 * 32 + cp);
        unpack_fma(acc, w0, v0);
    }
    uint4 o;
    o.x = f2bf(acc[0]) | (f2bf(acc[1]) << 16);
    o.y = f2bf(acc[2]) | (f2bf(acc[3]) << 16);
    o.z = f2bf(acc[4]) | (f2bf(acc[5]) << 16);
    o.w = f2bf(acc[6]) | (f2bf(acc[7]) << 16);
    *(uint4*)(x2 + (size_t)r * 32 + cp) = o;
}

// ---------------------------------------------------------------------------
// Final sampled layer, fused epilogue + ego.
// ---------------------------------------------------------------------------
__global__ void k_spmm3(const int* __restrict__ row_ptr, const int* __restrict__ pcol,
                        const int* __restrict__ dv,
                        const float* __restrict__ ue, const float* __restrict__ ie,
                        const unsigned* __restrict__ y1, const unsigned* __restrict__ x2,
                        const int* __restrict__ users, const int* __restrict__ pos,
                        const int* __restrict__ neg, float* __restrict__ out) {
    int tid = blockIdx.x * blockDim.x + threadIdx.x;
    int slot = tid >> 3;
    if (slot >= 3 * B) return;
    int cp = (tid & 7) << 2;          // uint base
    int c8 = (tid & 7) << 3;          // f32 col base
    int set = slot / B;
    int b = slot - set * B;
    int r;
    if (set == 0)      r = users[b];
    else if (set == 1) r = N_USERS + pos[b];
    else               r = N_USERS + neg[b];
    int s = row_ptr[r];
    int e = row_ptr[r + 1];
    int2 drs = *(const int2*)(dv + 2 * r);
    float dr = __int_as_float(drs.x);
    int sz = drs.y;
    float acc[8] = {0.f, 0.f, 0.f, 0.f, 0.f, 0.f, 0.f, 0.f};
    uint4 g1 = *(const uint4*)(y1 + (size_t)r * 32 + cp);
    uint4 g2 = *(const uint4*)(x2 + (size_t)r * 32 + cp);
    unpack_fma(acc, g1, 1.0f);
    unpack_fma(acc, g2, 1.0f);
    int i = s;
    for (; i + 1 < e; i += 2) {
        int c0 = pcol[i], c1 = pcol[i + 1];
        float v0 = dr * __int_as_float(dv[2 * c0]);
        float v1 = dr * __int_as_float(dv[2 * c1]);
        uint4 w0 = *(const uint4*)(x2 + (size_t)c0 * 32 + cp);
        uint4 w1 = *(const uint4*)(x2 + (size_t)c1 * 32 + cp);
        unpack_fma(acc, w0, v0);
        unpack_fma(acc, w1, v1);
    }
    if (i < e) {
        int c0 = pcol[i];
        float v0 = dr * __int_as_float(dv[2 * c0]);
        uint4 w0 = *(const uint4*)(x2 + (size_t)c0 * 32 + cp);
        unpack_fma(acc, w0, v0);
    }
    const float* p = ((r < N_USERS) ? ue + (size_t)r * D
                                    : ie + (size_t)(r - N_USERS) * D) + c8;
    float4 e0 = *(const float4*)p;
    float4 e1 = *(const float4*)(p + 4);
    e0.x = (c8 + 0 < sz) ? e0.x : 0.f; e0.y = (c8 + 1 < sz) ? e0.y : 0.f;
    e0.z = (c8 + 2 < sz) ? e0.z : 0.f; e0.w = (c8 + 3 < sz) ? e0.w : 0.f;
    e1.x = (c8 + 4 < sz) ? e1.x : 0.f; e1.y = (c8 + 5 < sz) ? e1.y : 0.f;
    e1.z = (c8 + 6 < sz) ? e1.z : 0.f; e1.w = (c8 + 7 < sz) ? e1.w : 0.f;
    float4 oa, ob;
    oa.x = (e0.x + acc[0]) * 0.25f; oa.y = (e0.y + acc[1]) * 0.25f;
    oa.z = (e0.z + acc[2]) * 0.25f; oa.w = (e0.w + acc[3]) * 0.25f;
    ob.x = (e1.x + acc[4]) * 0.25f; ob.y = (e1.y + acc[5]) * 0.25f;
    ob.z = (e1.z + acc[6]) * 0.25f; ob.w = (e1.w + acc[7]) * 0.25f;
    float* o0 = out + (size_t)slot * D + c8;
    float* o1 = out + (size_t)(3 * B + slot) * D + c8;
    *(float4*)o0 = oa; *(float4*)(o0 + 4) = ob;
    *(float4*)o1 = e0; *(float4*)(o1 + 4) = e1;
}

extern "C" void kernel_launch(void* const* d_in, const int* in_sizes, int n_in,
                              void* d_out, int out_size, void* d_ws, size_t ws_size,
                              hipStream_t stream) {
    const float* ue   = (const float*)d_in[0];
    const float* ie   = (const float*)d_in[1];
    const int*   um   = (const int*)d_in[2];
    const int*   im   = (const int*)d_in[3];
    const int*   rows = (const int*)d_in[4];
    const int*   cols = (const int*)d_in[5];
    const int*   users = (const int*)d_in[7];
    const int*   pos   = (const int*)d_in[8];
    const int*   neg   = (const int*)d_in[9];
    int nnz = in_sizes[4];

    float* out = (float*)d_out;

    // workspace layout (16B-aligned bf16 node buffers first)
    unsigned short* Y1 = (unsigned short*)d_ws;         // NNODES*D bf16
    unsigned short* X2 = Y1 + (size_t)NNODES * D;       // NNODES*D bf16
    int*   deg     = (int*)(X2 + (size_t)NNODES * D);   // NNODES
    int*   row_ptr = deg + NNODES;                      // NNODES+1
    int*   sums    = row_ptr + NNODES + 1;              // up to 4096
    int*   wcnt    = sums + 4096;                       // [0]=wl1_cnt [1]=wl2_cnt
    int*   cnt1    = wcnt + 16;                         // 2344 (+pad)
    int*   cnt2    = cnt1 + 2360;                       // 2344 (+pad)
    int*   dv      = (int*)(((uintptr_t)(cnt2 + 2360) + 7) & ~(uintptr_t)7); // 2*NNODES (packed {dinv,size})
    int*   pcol    = dv + 2 * NNODES;                   // nnz
    char*  flag1   = (char*)(pcol + nnz);               // NNODES
    char*  flag2   = flag1 + NNODES;                    // NNODES
    int*   wl1     = (int*)(((uintptr_t)(flag2 + NNODES) + 15) & ~(uintptr_t)15);
    int*   wl2     = wl1 + NNODES;
    int*   rank    = wl2 + NNODES;                      // nnz

    const int blk = 256;
    const int scan_blocks = (NNODES + 255) / 256;       // 2344
    int chunks = (nnz + 255) / 256;                     // 4688
    int nst = (chunks + 7) / 8;                         // 586 supertiles
    int nhist = chunks * 8;                             // hist blocks (chunk x bucket)
    int seed_blocks = (3 * B + blk - 1) / blk;          // 96
    int eb = (nnz + 1023) / 1024;                       // ILP-4 edge blocks (1172)
    int nsc = nst * 12 * 8;                             // fatS main grid
    // sizes coverage: nst*4*8 = 18752 >= 18750 blocks needed

    hipMemsetAsync(deg, 0, (size_t)NNODES * sizeof(int), stream);
    hipMemsetAsync(flag1, 0, (size_t)2 * NNODES, stream);

    // --- K1: histX + rank capture + seed (quiet L2 for atomics) ---
    k_hrs<<<nhist + seed_blocks, blk, 0, stream>>>(rows, deg, rank,
                                                   users, pos, neg,
                                                   flag1, flag2, nnz, nhist);

    // --- scan1(+dinv->dv) || pass1(ILP-4) ---
    k_s1p1<<<scan_blocks + eb, blk, 0, stream>>>(deg, sums, dv,
                                                 rows, cols, flag2, nnz, scan_blocks);

    // --- scan2 ---
    k_scan2<<<1, 1024, 0, stream>>>(sums, scan_blocks);

    // --- scan3 || pass2(ILP-4) || flag-tail(+cnt2) ---
    k_s3p2<<<scan_blocks + eb + scan_blocks, blk, 0, stream>>>(
        deg, sums, row_ptr, rows, cols, flag2, flag1, cnt2, nnz, scan_blocks, eb);

    // --- cnt1 + dual scan (small, ahead of K2 so fill can ride K2) ---
    k_cnt1<<<scan_blocks, blk, 0, stream>>>(flag1, cnt1);
    k_scan_dual<<<1, 1024, 0, stream>>>(cnt1, cnt2, scan_blocks, wcnt, wcnt + 1);

    // --- K2: det scatter || cond-half mask stream (sizes->dv) || fill tail ---
    k_fatS<<<nsc + scan_blocks, blk, 0, stream>>>(rows, cols, rank, row_ptr, pcol,
                                                  um, im, dv, flag1, flag2,
                                                  cnt1, cnt2, wl1, wl2,
                                                  nnz, nsc);

    int n_full = NNODES * 8;
    int n_samp = 3 * B * 8;

    // layer 1 over wl1 (dense sorted waves)
    k_spmm1<<<(n_full + blk - 1) / blk, blk, 0, stream>>>(row_ptr, pcol, dv,
                                                          wl1, wcnt,
                                                          ue, ie, (unsigned*)Y1);
    // layer 2 over wl2 (dense sorted waves)
    k_spmm2<<<(n_full + blk - 1) / blk, blk, 0, stream>>>(row_ptr, pcol, dv,
                                                          wl2, wcnt + 1,
                                                          (const unsigned*)Y1, (unsigned*)X2);
    // layer 3: sampled rows, fused epilogue + ego
    k_spmm3<<<(n_samp + blk - 1) / blk, blk, 0, stream>>>(row_ptr, pcol, dv,
                                                          ue, ie,
                                                          (const unsigned*)Y1,
                                                          (const unsigned*)X2,
                                                          users, pos, neg, out);
}

// Round 16
// 209.843 us; speedup vs baseline: 1.2495x; 1.0017x over previous
//
#include <hip/hip_runtime.h>

#define N_USERS 400000
#define N_ITEMS 200000
#define NNODES  600000   // N_USERS + N_ITEMS
#define D 64
#define B 8192
#define NBKT 8

typedef int v4i __attribute__((ext_vector_type(4)));

// ---------------------------------------------------------------------------
// bf16 helpers
// ---------------------------------------------------------------------------
__device__ __forceinline__ float bflo(unsigned u) { return __uint_as_float(u << 16); }
__device__ __forceinline__ float bfhi(unsigned u) { return __uint_as_float(u & 0xffff0000u); }
__device__ __forceinline__ unsigned f2bf(float f) {   // round-to-nearest-even
    unsigned u = __float_as_uint(f);
    unsigned r = u + 0x7fffu + ((u >> 16) & 1u);
    return r >> 16;
}

// acc[0..7] += v * bf16x8(word4)
__device__ __forceinline__ void unpack_fma(float* acc, uint4 wv, float v) {
    acc[0] += v * bflo(wv.x); acc[1] += v * bfhi(wv.x);
    acc[2] += v * bflo(wv.y); acc[3] += v * bfhi(wv.y);
    acc[4] += v * bflo(wv.z); acc[5] += v * bfhi(wv.z);
    acc[6] += v * bflo(wv.w); acc[7] += v * bfhi(wv.w);
}

// Bucket map balanced by expected edge count.
__device__ __forceinline__ int bucket_of(int r) {
    return (r < N_USERS) ? (r / 100000) : (4 + (r - N_USERS) / 50000);
}

// ---------------------------------------------------------------------------
// K1: XCD-filtered hist + rank capture (validated R13) + sample seed.
// ---------------------------------------------------------------------------
__global__ void k_hrs(const int* __restrict__ rows, int* __restrict__ deg,
                      int* __restrict__ rank,
                      const int* __restrict__ users, const int* __restrict__ pos,
                      const int* __restrict__ neg,
                      char* __restrict__ flag1, char* __restrict__ flag2,
                      int nnz, int nhist) {
    int bid = blockIdx.x;
    int t = threadIdx.x;
    if (bid < nhist) {
        int x = bid & 7;
        int e = (bid >> 3) * 256 + t;
        if (e >= nnz) return;
        int r = rows[e];
        if (bucket_of(r) == x) rank[e] = atomicAdd(&deg[r], 1);
    } else {
        int slot2 = (bid - nhist) * 256 + t;
        if (slot2 >= 3 * B) return;
        int set = slot2 / B;
        int b = slot2 - set * B;
        int r;
        if (set == 0)      r = users[b];
        else if (set == 1) r = N_USERS + pos[b];
        else               r = N_USERS + neg[b];
        flag2[r] = 1;
        flag1[r] = 1;
    }
}

// ---------------------------------------------------------------------------
// s1p1: scan1 (per-block excl scan of deg; dinv -> dv[2r].x) || pass1 (ILP-4).
// pass1 race: monotone 0->1, benign superset.
// ---------------------------------------------------------------------------
__global__ void k_s1p1(int* __restrict__ deg, int* __restrict__ sums,
                       int* __restrict__ dv,
                       const int* __restrict__ rows, const int* __restrict__ cols,
                       char* __restrict__ flag2, int nnz, int scan_blocks) {
    int bid = blockIdx.x;
    int t = threadIdx.x;
    if (bid < scan_blocks) {
        __shared__ int lds[256];
        int i = bid * 256 + t;
        int v = (i < NNODES) ? deg[i] : 0;
        if (i < NNODES) {
            float dvf = (v > 0) ? (float)(1.0 / sqrt((double)v)) : 0.0f;
            dv[2 * i] = __float_as_int(dvf);
        }
        lds[t] = v;
        __syncthreads();
        for (int off = 1; off < 256; off <<= 1) {
            int tv = (t >= off) ? lds[t - off] : 0;
            __syncthreads();
            lds[t] += tv;
            __syncthreads();
        }
        int inc = lds[t];
        if (i < NNODES) deg[i] = inc - v;
        if (t == 255) sums[bid] = inc;
    } else {
        int base = (bid - scan_blocks) * 1024 + t;
        int r4[4], c4[4];
        #pragma unroll
        for (int k = 0; k < 4; ++k) {
            int e = base + k * 256;
            r4[k] = (e < nnz) ? rows[e] : -1;
            c4[k] = (e < nnz) ? cols[e] : 0;
        }
        char f4[4];
        #pragma unroll
        for (int k = 0; k < 4; ++k) f4[k] = (r4[k] >= 0) ? flag2[r4[k]] : (char)0;
        #pragma unroll
        for (int k = 0; k < 4; ++k) if (f4[k]) flag2[c4[k]] = 1;
    }
}

__global__ void k_scan2(int* __restrict__ sums, int n) {
    __shared__ int lds[1024];
    __shared__ int carry;
    if (threadIdx.x == 0) carry = 0;
    __syncthreads();
    for (int base = 0; base < n; base += 1024) {
        int i = base + threadIdx.x;
        int v = (i < n) ? sums[i] : 0;
        lds[threadIdx.x] = v;
        __syncthreads();
        for (int off = 1; off < 1024; off <<= 1) {
            int t = (threadIdx.x >= off) ? lds[threadIdx.x - off] : 0;
            __syncthreads();
            lds[threadIdx.x] += t;
            __syncthreads();
        }
        int inc = lds[threadIdx.x];
        if (i < n) sums[i] = (inc - v) + carry;
        __syncthreads();
        if (threadIdx.x == 1023) carry += lds[1023];
        __syncthreads();
    }
}

// ---------------------------------------------------------------------------
// s3p2: scan3 (row_ptr) || mark-pass2 (ILP-4) || flag-tail(+cnt2).
// ---------------------------------------------------------------------------
__global__ void k_s3p2(const int* __restrict__ deg, const int* __restrict__ sums,
                       int* __restrict__ row_ptr,
                       const int* __restrict__ rows, const int* __restrict__ cols,
                       const char* __restrict__ flag2, char* __restrict__ flag1,
                       int* __restrict__ cnt2, int nnz, int scan_blocks, int eb) {
    int bid = blockIdx.x;
    int t = threadIdx.x;
    if (bid < scan_blocks) {
        int i = bid * 256 + t;
        if (i >= NNODES) return;
        row_ptr[i] = deg[i] + sums[i >> 8];
        if (i == 0) row_ptr[NNODES] = nnz;
    } else if (bid < scan_blocks + eb) {
        int base = (bid - scan_blocks) * 1024 + t;
        int r4[4], c4[4];
        #pragma unroll
        for (int k = 0; k < 4; ++k) {
            int e = base + k * 256;
            r4[k] = (e < nnz) ? rows[e] : -1;
            c4[k] = (e < nnz) ? cols[e] : 0;
        }
        char f4[4];
        #pragma unroll
        for (int k = 0; k < 4; ++k) f4[k] = (r4[k] >= 0) ? flag2[r4[k]] : (char)0;
        #pragma unroll
        for (int k = 0; k < 4; ++k) if (f4[k]) flag1[c4[k]] = 1;
    } else {
        int tb = bid - scan_blocks - eb;
        int r = tb * 256 + t;
        char f = (r < NNODES) ? flag2[r] : 0;
        if (f) flag1[r] = 1;
        unsigned long long bal = __ballot(f != 0);
        __shared__ int ws[4];
        int lane = t & 63, wv = t >> 6;
        if (lane == 0) ws[wv] = (int)__popcll(bal);
        __syncthreads();
        if (t == 0) cnt2[tb] = ws[0] + ws[1] + ws[2] + ws[3];
    }
}

// per-block flag1 counts (flag1 final after s3p2)
__global__ void k_cnt1(const char* __restrict__ flag1, int* __restrict__ cnt1) {
    int tb = blockIdx.x;
    int t = threadIdx.x;
    int r = tb * 256 + t;
    char f = (r < NNODES) ? flag1[r] : 0;
    unsigned long long bal = __ballot(f != 0);
    __shared__ int ws[4];
    int lane = t & 63, wv = t >> 6;
    if (lane == 0) ws[wv] = (int)__popcll(bal);
    __syncthreads();
    if (t == 0) cnt1[tb] = ws[0] + ws[1] + ws[2] + ws[3];
}

// single-block exclusive scan of TWO count arrays (in place) + totals
__global__ void k_scan_dual(int* __restrict__ a, int* __restrict__ b, int n,
                            int* __restrict__ totA, int* __restrict__ totB) {
    __shared__ int lds[1024];
    __shared__ int carry;
    for (int pass = 0; pass < 2; ++pass) {
        int* arr = pass ? b : a;
        if (threadIdx.x == 0) carry = 0;
        __syncthreads();
        for (int base = 0; base < n; base += 1024) {
            int i = base + threadIdx.x;
            int v = (i < n) ? arr[i] : 0;
            lds[threadIdx.x] = v;
            __syncthreads();
            for (int off = 1; off < 1024; off <<= 1) {
                int t = (threadIdx.x >= off) ? lds[threadIdx.x - off] : 0;
                __syncthreads();
                lds[threadIdx.x] += t;
                __syncthreads();
            }
            int inc = lds[threadIdx.x];
            if (i < n) arr[i] = (inc - v) + carry;
            __syncthreads();
            if (threadIdx.x == 1023) carry += lds[1023];
            __syncthreads();
        }
        if (threadIdx.x == 0) { if (pass) *totB = carry; else *totA = carry; }
        __syncthreads();
    }
}

// ---------------------------------------------------------------------------
// K2: deterministic scatter || conditional-half mask stream (sizes->dv) ||
// ballot-rank fill tail. (R13-R15 validated structure.)
// ---------------------------------------------------------------------------
__global__ void k_fatS(const int* __restrict__ rows, const int* __restrict__ cols,
                       const int* __restrict__ rank, const int* __restrict__ row_ptr,
                       int* __restrict__ pcol,
                       const int* __restrict__ um, const int* __restrict__ im,
                       int* __restrict__ dv,
                       const char* __restrict__ flag1, const char* __restrict__ flag2,
                       const int* __restrict__ cnt1, const int* __restrict__ cnt2,
                       int* __restrict__ wl1, int* __restrict__ wl2,
                       int nnz, int nsc) {
    int bid = blockIdx.x;
    int t = threadIdx.x;
    if (bid >= nsc) {
        // fill tail
        int tb = bid - nsc;
        int r = tb * 256 + t;
        bool a = (r < NNODES) && flag1[r];
        bool b = (r < NNODES) && flag2[r];
        int lane = t & 63, wv = t >> 6;
        unsigned long long lt = (1ull << lane) - 1ull;
        unsigned long long ba = __ballot(a);
        unsigned long long bb = __ballot(b);
        __shared__ int wa[4], wb[4];
        if (lane == 0) { wa[wv] = (int)__popcll(ba); wb[wv] = (int)__popcll(bb); }
        __syncthreads();
        int offA = 0, offB = 0;
        for (int i = 0; i < wv; ++i) { offA += wa[i]; offB += wb[i]; }
        if (a) wl1[cnt1[tb] + offA + (int)__popcll(ba & lt)] = r;
        if (b) wl2[cnt2[tb] + offB + (int)__popcll(bb & lt)] = r;
        return;
    }
    int x = bid & 7;
    int g = bid >> 3;
    int st = g / 12;
    int slot = g - st * 12;
    if (slot < 8) {
        int e = (st * 8 + slot) * 256 + t;
        if (e >= nnz) return;
        int r = rows[e];
        if (bucket_of(r) != x) return;
        pcol[row_ptr[r] + rank[e]] = cols[e];
    } else {
        int sb = (st * 4 + (slot - 8)) * 8 + x;
        int r = sb * 32 + (t >> 3);
        int q = t & 7;
        if (r >= NNODES) return;
        const v4i* p = (const v4i*)((r < N_USERS) ? um + (size_t)r * D
                                                  : im + (size_t)(r - N_USERS) * D);
        v4i v0 = __builtin_nontemporal_load(p + q);        // first 128B of row
        int s = v0[0] + v0[1] + v0[2] + v0[3];
        int lane = t & 63;
        int m31 = __shfl(v0[3], (lane & 56) | 7, 64);
        if (m31) {
            v4i v1 = __builtin_nontemporal_load(p + 8 + q);
            s += v1[0] + v1[1] + v1[2] + v1[3];
        }
        s += __shfl_xor(s, 1);
        s += __shfl_xor(s, 2);
        s += __shfl_xor(s, 4);
        if (q == 0) dv[2 * r + 1] = s;
    }
}

// masked embedding fetch helper: acc += v * masked(emb row half-pair)
__device__ __forceinline__ void emb_fma(float* acc, const float* __restrict__ ue,
                                        const float* __restrict__ ie,
                                        int c, int c8, float v, int sz) {
    const float* p = ((c < N_USERS) ? ue + (size_t)c * D
                                    : ie + (size_t)(c - N_USERS) * D) + c8;
    float4 e0 = *(const float4*)p;
    float4 e1 = *(const float4*)(p + 4);
    acc[0] += v * ((c8 + 0 < sz) ? e0.x : 0.f);
    acc[1] += v * ((c8 + 1 < sz) ? e0.y : 0.f);
    acc[2] += v * ((c8 + 2 < sz) ? e0.z : 0.f);
    acc[3] += v * ((c8 + 3 < sz) ? e0.w : 0.f);
    acc[4] += v * ((c8 + 4 < sz) ? e1.x : 0.f);
    acc[5] += v * ((c8 + 5 < sz) ? e1.y : 0.f);
    acc[6] += v * ((c8 + 6 < sz) ? e1.z : 0.f);
    acc[7] += v * ((c8 + 7 < sz) ? e1.w : 0.f);
}

// ---------------------------------------------------------------------------
// Layer-1 SPMM over wl1. 8 threads/row, ILP-4 edge chains (batched pcol/dv
// loads -> 4 independent gather chains in flight; latency-bound lever).
// ---------------------------------------------------------------------------
__global__ void k_spmm1(const int* __restrict__ row_ptr, const int* __restrict__ pcol,
                        const int* __restrict__ dv,
                        const int* __restrict__ wl1, const int* __restrict__ wl1_cnt,
                        const float* __restrict__ ue, const float* __restrict__ ie,
                        unsigned* __restrict__ y1) {
    int tid = blockIdx.x * blockDim.x + threadIdx.x;
    int w = tid >> 3;
    if (w >= *wl1_cnt) return;
    int r = wl1[w];
    int c8 = (tid & 7) << 3;          // f32 col base
    int s = row_ptr[r];
    int e = row_ptr[r + 1];
    float dr = __int_as_float(dv[2 * r]);
    float acc[8] = {0.f, 0.f, 0.f, 0.f, 0.f, 0.f, 0.f, 0.f};
    int i = s;
    for (; i + 3 < e; i += 4) {
        int c0 = pcol[i], c1 = pcol[i + 1], c2 = pcol[i + 2], c3 = pcol[i + 3];
        int2 d0 = *(const int2*)(dv + 2 * c0);
        int2 d1 = *(const int2*)(dv + 2 * c1);
        int2 d2 = *(const int2*)(dv + 2 * c2);
        int2 d3 = *(const int2*)(dv + 2 * c3);
        emb_fma(acc, ue, ie, c0, c8, dr * __int_as_float(d0.x), d0.y);
        emb_fma(acc, ue, ie, c1, c8, dr * __int_as_float(d1.x), d1.y);
        emb_fma(acc, ue, ie, c2, c8, dr * __int_as_float(d2.x), d2.y);
        emb_fma(acc, ue, ie, c3, c8, dr * __int_as_float(d3.x), d3.y);
    }
    for (; i < e; ++i) {
        int c = pcol[i];
        int2 d0 = *(const int2*)(dv + 2 * c);
        emb_fma(acc, ue, ie, c, c8, dr * __int_as_float(d0.x), d0.y);
    }
    uint4 o;
    o.x = f2bf(acc[0]) | (f2bf(acc[1]) << 16);
    o.y = f2bf(acc[2]) | (f2bf(acc[3]) << 16);
    o.z = f2bf(acc[4]) | (f2bf(acc[5]) << 16);
    o.w = f2bf(acc[6]) | (f2bf(acc[7]) << 16);
    *(uint4*)(y1 + (size_t)r * 32 + (tid & 7) * 4) = o;
}

// ---------------------------------------------------------------------------
// Layer-2 bf16 SPMM over wl2: ILP-4 edge chains.
// ---------------------------------------------------------------------------
__global__ void k_spmm2(const int* __restrict__ row_ptr, const int* __restrict__ pcol,
                        const int* __restrict__ dv,
                        const int* __restrict__ wl2, const int* __restrict__ wl2_cnt,
                        const unsigned* __restrict__ y1, unsigned* __restrict__ x2) {
    int tid = blockIdx.x * blockDim.x + threadIdx.x;
    int w = tid >> 3;
    if (w >= *wl2_cnt) return;
    int r = wl2[w];
    int cp = (tid & 7) << 2;
    int s = row_ptr[r];
    int e = row_ptr[r + 1];
    float dr = __int_as_float(dv[2 * r]);
    float acc[8] = {0.f, 0.f, 0.f, 0.f, 0.f, 0.f, 0.f, 0.f};
    int i = s;
    for (; i + 3 < e; i += 4) {
        int c0 = pcol[i], c1 = pcol[i + 1], c2 = pcol[i + 2], c3 = pcol[i + 3];
        float v0 = dr * __int_as_float(dv[2 * c0]);
        float v1 = dr * __int_as_float(dv[2 * c1]);
        float v2 = dr * __int_as_float(dv[2 * c2]);
        float v3 = dr * __int_as_float(dv[2 * c3]);
        uint4 w0 = *(const uint4*)(y1 + (size_t)c0 * 32 + cp);
        uint4 w1 = *(const uint4*)(y1 + (size_t)c1 * 32 + cp);
        uint4 w2 = *(const uint4*)(y1 + (size_t)c2 * 32 + cp);
        uint4 w3 = *(const uint4*)(y1 + (size_t)c3 * 32 + cp);
        unpack_fma(acc, w0, v0);
        unpack_fma(acc, w1, v1);
        unpack_fma(acc, w2, v2);
        unpack_fma(acc, w3, v3);
    }
    for (; i < e; ++i) {
        int c0 = pcol[i];
        float v0 = dr * __int_as_float(dv[2 * c0]);
        uint4 w0 = *(const uint4*)(y1 + (size_t)c0 * 32 + cp);
        unpack_fma(acc, w0, v0);
    }
    uint4 o;
    o.x = f2bf(acc[0]) | (f2bf(acc[1]) << 16);
    o.y = f2bf(acc[2]) | (f2bf(acc[3]) << 16);
    o.z = f2bf(acc[4]) | (f2bf(acc[5]) << 16);
    o.w = f2bf(acc[6]) | (f2bf(acc[7]) << 16);
    *(uint4*)(x2 + (size_t)r * 32 + cp) = o;
}

// ---------------------------------------------------------------------------
// Final sampled layer, fused epilogue + ego. ILP-4 x2 loop.
// ---------------------------------------------------------------------------
__global__ void k_spmm3(const int* __restrict__ row_ptr, const int* __restrict__ pcol,
                        const int* __restrict__ dv,
                        const float* __restrict__ ue, const float* __restrict__ ie,
                        const unsigned* __restrict__ y1, const unsigned* __restrict__ x2,
                        const int* __restrict__ users, const int* __restrict__ pos,
                        const int* __restrict__ neg, float* __restrict__ out) {
    int tid = blockIdx.x * blockDim.x + threadIdx.x;
    int slot = tid >> 3;
    if (slot >= 3 * B) return;
    int cp = (tid & 7) << 2;          // uint base
    int c8 = (tid & 7) << 3;          // f32 col base
    int set = slot / B;
    int b = slot - set * B;
    int r;
    if (set == 0)      r = users[b];
    else if (set == 1) r = N_USERS + pos[b];
    else               r = N_USERS + neg[b];
    int s = row_ptr[r];
    int e = row_ptr[r + 1];
    int2 drs = *(const int2*)(dv + 2 * r);
    float dr = __int_as_float(drs.x);
    int sz = drs.y;
    float acc[8] = {0.f, 0.f, 0.f, 0.f, 0.f, 0.f, 0.f, 0.f};
    uint4 g1 = *(const uint4*)(y1 + (size_t)r * 32 + cp);
    uint4 g2 = *(const uint4*)(x2 + (size_t)r * 32 + cp);
    unpack_fma(acc, g1, 1.0f);
    unpack_fma(acc, g2, 1.0f);
    int i = s;
    for (; i + 3 < e; i += 4) {
        int c0 = pcol[i], c1 = pcol[i + 1], c2 = pcol[i + 2], c3 = pcol[i + 3];
        float v0 = dr * __int_as_float(dv[2 * c0]);
        float v1 = dr * __int_as_float(dv[2 * c1]);
        float v2 = dr * __int_as_float(dv[2 * c2]);
        float v3 = dr * __int_as_float(dv[2 * c3]);
        uint4 w0 = *(const uint4*)(x2 + (size_t)c0 * 32 + cp);
        uint4 w1 = *(const uint4*)(x2 + (size_t)c1 * 32 + cp);
        uint4 w2 = *(const uint4*)(x2 + (size_t)c2 * 32 + cp);
        uint4 w3 = *(const uint4*)(x2 + (size_t)c3 * 32 + cp);
        unpack_fma(acc, w0, v0);
        unpack_fma(acc, w1, v1);
        unpack_fma(acc, w2, v2);
        unpack_fma(acc, w3, v3);
    }
    for (; i < e; ++i) {
        int c0 = pcol[i];
        float v0 = dr * __int_as_float(dv[2 * c0]);
        uint4 w0 = *(const uint4*)(x2 + (size_t)c0 * 32 + cp);
        unpack_fma(acc, w0, v0);
    }
    const float* p = ((r < N_USERS) ? ue + (size_t)r * D
                                    : ie + (size_t)(r - N_USERS) * D) + c8;
    float4 e0 = *(const float4*)p;
    float4 e1 = *(const float4*)(p + 4);
    e0.x = (c8 + 0 < sz) ? e0.x : 0.f; e0.y = (c8 + 1 < sz) ? e0.y : 0.f;
    e0.z = (c8 + 2 < sz) ? e0.z : 0.f; e0.w = (c8 + 3 < sz) ? e0.w : 0.f;
    e1.x = (c8 + 4 < sz) ? e1.x : 0.f; e1.y = (c8 + 5 < sz) ? e1.y : 0.f;
    e1.z = (c8 + 6 < sz) ? e1.z : 0.f; e1.w = (c8 + 7 < sz) ? e1.w : 0.f;
    float4 oa, ob;
    oa.x = (e0.x + acc[0]) * 0.25f; oa.y = (e0.y + acc[1]) * 0.25f;
    oa.z = (e0.z + acc[2]) * 0.25f; oa.w = (e0.w + acc[3]) * 0.25f;
    ob.x = (e1.x + acc[4]) * 0.25f; ob.y = (e1.y + acc[5]) * 0.25f;
    ob.z = (e1.z + acc[6]) * 0.25f; ob.w = (e1.w + acc[7]) * 0.25f;
    float* o0 = out + (size_t)slot * D + c8;
    float* o1 = out + (size_t)(3 * B + slot) * D + c8;
    *(float4*)o0 = oa; *(float4*)(o0 + 4) = ob;
    *(float4*)o1 = e0; *(float4*)(o1 + 4) = e1;
}

extern "C" void kernel_launch(void* const* d_in, const int* in_sizes, int n_in,
                              void* d_out, int out_size, void* d_ws, size_t ws_size,
                              hipStream_t stream) {
    const float* ue   = (const float*)d_in[0];
    const float* ie   = (const float*)d_in[1];
    const int*   um   = (const int*)d_in[2];
    const int*   im   = (const int*)d_in[3];
    const int*   rows = (const int*)d_in[4];
    const int*   cols = (const int*)d_in[5];
    const int*   users = (const int*)d_in[7];
    const int*   pos   = (const int*)d_in[8];
    const int*   neg   = (const int*)d_in[9];
    int nnz = in_sizes[4];

    float* out = (float*)d_out;

    // workspace layout (16B-aligned bf16 node buffers first)
    unsigned short* Y1 = (unsigned short*)d_ws;         // NNODES*D bf16
    unsigned short* X2 = Y1 + (size_t)NNODES * D;       // NNODES*D bf16
    int*   deg     = (int*)(X2 + (size_t)NNODES * D);   // NNODES
    int*   row_ptr = deg + NNODES;                      // NNODES+1
    int*   sums    = row_ptr + NNODES + 1;              // up to 4096
    int*   wcnt    = sums + 4096;                       // [0]=wl1_cnt [1]=wl2_cnt
    int*   cnt1    = wcnt + 16;                         // 2344 (+pad)
    int*   cnt2    = cnt1 + 2360;                       // 2344 (+pad)
    int*   dv      = (int*)(((uintptr_t)(cnt2 + 2360) + 7) & ~(uintptr_t)7); // 2*NNODES (packed {dinv,size})
    int*   pcol    = dv + 2 * NNODES;                   // nnz
    char*  flag1   = (char*)(pcol + nnz);               // NNODES
    char*  flag2   = flag1 + NNODES;                    // NNODES
    int*   wl1     = (int*)(((uintptr_t)(flag2 + NNODES) + 15) & ~(uintptr_t)15);
    int*   wl2     = wl1 + NNODES;
    int*   rank    = wl2 + NNODES;                      // nnz

    const int blk = 256;
    const int scan_blocks = (NNODES + 255) / 256;       // 2344
    int chunks = (nnz + 255) / 256;                     // 4688
    int nst = (chunks + 7) / 8;                         // 586 supertiles
    int nhist = chunks * 8;                             // hist blocks (chunk x bucket)
    int seed_blocks = (3 * B + blk - 1) / blk;          // 96
    int eb = (nnz + 1023) / 1024;                       // ILP-4 edge blocks (1172)
    int nsc = nst * 12 * 8;                             // fatS main grid
    // sizes coverage: nst*4*8 = 18752 >= 18750 blocks needed

    hipMemsetAsync(deg, 0, (size_t)NNODES * sizeof(int), stream);
    hipMemsetAsync(flag1, 0, (size_t)2 * NNODES, stream);

    // --- K1: histX + rank capture + seed (quiet L2 for atomics) ---
    k_hrs<<<nhist + seed_blocks, blk, 0, stream>>>(rows, deg, rank,
                                                   users, pos, neg,
                                                   flag1, flag2, nnz, nhist);

    // --- scan1(+dinv->dv) || pass1(ILP-4) ---
    k_s1p1<<<scan_blocks + eb, blk, 0, stream>>>(deg, sums, dv,
                                                 rows, cols, flag2, nnz, scan_blocks);

    // --- scan2 ---
    k_scan2<<<1, 1024, 0, stream>>>(sums, scan_blocks);

    // --- scan3 || pass2(ILP-4) || flag-tail(+cnt2) ---
    k_s3p2<<<scan_blocks + eb + scan_blocks, blk, 0, stream>>>(
        deg, sums, row_ptr, rows, cols, flag2, flag1, cnt2, nnz, scan_blocks, eb);

    // --- cnt1 + dual scan (ahead of K2 so fill rides K2) ---
    k_cnt1<<<scan_blocks, blk, 0, stream>>>(flag1, cnt1);
    k_scan_dual<<<1, 1024, 0, stream>>>(cnt1, cnt2, scan_blocks, wcnt, wcnt + 1);

    // --- K2: det scatter || cond-half mask stream (sizes->dv) || fill tail ---
    k_fatS<<<nsc + scan_blocks, blk, 0, stream>>>(rows, cols, rank, row_ptr, pcol,
                                                  um, im, dv, flag1, flag2,
                                                  cnt1, cnt2, wl1, wl2,
                                                  nnz, nsc);

    int n_full = NNODES * 8;
    int n_samp = 3 * B * 8;

    // layer 1 over wl1 (dense sorted waves, ILP-4)
    k_spmm1<<<(n_full + blk - 1) / blk, blk, 0, stream>>>(row_ptr, pcol, dv,
                                                          wl1, wcnt,
                                                          ue, ie, (unsigned*)Y1);
    // layer 2 over wl2 (dense sorted waves, ILP-4)
    k_spmm2<<<(n_full + blk - 1) / blk, blk, 0, stream>>>(row_ptr, pcol, dv,
                                                          wl2, wcnt + 1,
                                                          (const unsigned*)Y1, (unsigned*)X2);
    // layer 3: sampled rows, fused epilogue + ego (ILP-4)
    k_spmm3<<<(n_samp + blk - 1) / blk, blk, 0, stream>>>(row_ptr, pcol, dv,
                                                          ue, ie,
                                                          (const unsigned*)Y1,
                                                          (const unsigned*)X2,
                                                          users, pos, neg, out);
}